// Round 13
// baseline (136.725 us; speedup 1.0000x reference)
//
#include <hip/hip_runtime.h>
#include <hip/hip_bf16.h>
#include <stdint.h>

typedef __hip_bfloat16 bf16;
typedef __attribute__((ext_vector_type(8))) short short8;
typedef __attribute__((ext_vector_type(4))) short bf16x4;
typedef __attribute__((ext_vector_type(4))) float f32x4;

#define EPS_ATTN 1e-6f
#define EPS_LN   1e-5f

__device__ __forceinline__ float b2f(short s) {
    return __builtin_bit_cast(float, (unsigned)((unsigned short)s) << 16);
}
__device__ __forceinline__ short f2b(float f) {
    return __builtin_bit_cast(short, __float2bfloat16(f));
}

// ---------------------------------------------------------------------------
// async global->LDS, 16B per lane. LDS dest = wave-uniform base + lane*16.
// ---------------------------------------------------------------------------
__device__ __forceinline__ void async16(const void* g, void* l) {
    __builtin_amdgcn_global_load_lds(
        (const __attribute__((address_space(1))) void*)g,
        (__attribute__((address_space(3))) void*)l,
        16, 0, 0);
}

// ---------------------------------------------------------------------------
// Prep: fp32->bf16 converts (x, source) + all 6 weight transposes, ONE launch.
// ---------------------------------------------------------------------------
__global__ __launch_bounds__(256)
void k_prep(const float* __restrict__ x, const float* __restrict__ src,
            bf16* __restrict__ x_bf, bf16* __restrict__ s_bf,
            const float* __restrict__ Wq, const float* __restrict__ Wk,
            const float* __restrict__ Wv, const float* __restrict__ Wm,
            const float* __restrict__ W1, const float* __restrict__ W2,
            bf16* __restrict__ WqT, bf16* __restrict__ WkT,
            bf16* __restrict__ WvT, bf16* __restrict__ WmT,
            bf16* __restrict__ W1T, bf16* __restrict__ W2T)
{
    __shared__ float tile[64][65];
    const int blk = blockIdx.x;
    if (blk < 8192) {
        const float* in = (blk < 4096) ? x : src;
        bf16* out       = (blk < 4096) ? x_bf : s_bf;
        const long id = (long)(blk & 4095) * 256 + threadIdx.x;
        const float4 a = ((const float4*)in)[id * 2];
        const float4 b = ((const float4*)in)[id * 2 + 1];
        short8 o;
        o[0] = f2b(a.x); o[1] = f2b(a.y); o[2] = f2b(a.z); o[3] = f2b(a.w);
        o[4] = f2b(b.x); o[5] = f2b(b.y); o[6] = f2b(b.z); o[7] = f2b(b.w);
        ((short8*)out)[id] = o;
        return;
    }
    const int b = blk - 8192;
    const float* W; bf16* WT; int K, N, local;
    if      (b < 16)  { W = Wq; WT = WqT; K = 256; N = 256; local = b; }
    else if (b < 32)  { W = Wk; WT = WkT; K = 256; N = 256; local = b - 16; }
    else if (b < 48)  { W = Wv; WT = WvT; K = 256; N = 256; local = b - 32; }
    else if (b < 64)  { W = Wm; WT = WmT; K = 256; N = 256; local = b - 48; }
    else if (b < 128) { W = W1; WT = W1T; K = 512; N = 512; local = b - 64; }
    else              { W = W2; WT = W2T; K = 512; N = 256; local = b - 128; }
    const int tk = K / 64;
    const int k0 = (local % tk) * 64, n0 = (local / tk) * 64;
    const int ty = threadIdx.x >> 4, tx = threadIdx.x & 15;
    #pragma unroll
    for (int i = 0; i < 4; ++i) {
        const int k = ty + i * 16;
        const float4 v = *(const float4*)&W[(long)(k0 + k) * N + n0 + tx * 4];
        tile[k][tx * 4 + 0] = v.x; tile[k][tx * 4 + 1] = v.y;
        tile[k][tx * 4 + 2] = v.z; tile[k][tx * 4 + 3] = v.w;
    }
    __syncthreads();
    #pragma unroll
    for (int i = 0; i < 4; ++i) {
        const int n = ty + i * 16;
        bf16x4 o;
        #pragma unroll
        for (int j = 0; j < 4; ++j) o[j] = f2b(tile[tx * 4 + j][n]);
        *(bf16x4*)&WT[(long)(n0 + n) * K + k0 + tx * 4] = o;
    }
}

// ---------------------------------------------------------------------------
// FUSED K/V projection + feature-map + partial-KV/Ksum (proven in R9).
// ---------------------------------------------------------------------------
__global__ __launch_bounds__(512)
void k_kvproj(const bf16* __restrict__ A, const bf16* __restrict__ BT,
              bf16* __restrict__ partKV, float* __restrict__ partKs,
              float escale)
{
    __shared__ __attribute__((aligned(16))) bf16 S[32768];   // 64 KB union
    bf16* Asm = S;
    bf16* Bsm = S + 8192;
    bf16* KT  = S;
    bf16* VT  = S + 16384;

    const int t = threadIdx.x, w = t >> 6, lane = t & 63;
    const int wm = w >> 2, wn = w & 3;
    const int flat = blockIdx.y * gridDim.x + blockIdx.x;   // 0..511
    const int swz  = (flat & 7) * 64 + (flat >> 3);         // bijective, XCD
    const int cid  = swz >> 1;
    const int hh   = swz & 1;
    const long row0 = (long)cid * 128;
    const int lr = lane >> 3, lc = (lane & 7) * 8;
    const int lg = lane >> 4, l15 = lane & 15;

    f32x4 acc[4][4] = {};

    for (int kt = 0; kt < 256; kt += 64) {
        #pragma unroll
        for (int i = 0; i < 2; ++i) {
            const int g = w * 2 + i;
            async16(A + (row0 + g * 8 + lr) * 256 + kt + lc, &Asm[g * 512]);
        }
        #pragma unroll
        for (int i = 0; i < 4; ++i) {
            const int g = w * 4 + i;
            const long brow = (g < 16)
                ? (long)(hh * 128 + g * 8 + lr)
                : (long)(256 + hh * 128 + (g - 16) * 8 + lr);
            async16(BT + brow * 256 + kt + lc, &Bsm[g * 512]);
        }
        __syncthreads();
        #pragma unroll
        for (int ks = 0; ks < 2; ++ks) {
            short8 a[4], b[4];
            #pragma unroll
            for (int m = 0; m < 4; ++m)
                a[m] = *(const short8*)&Asm[(wm*64 + m*16 + l15)*64 + ks*32 + lg*8];
            #pragma unroll
            for (int n = 0; n < 4; ++n)
                b[n] = *(const short8*)&Bsm[(wn*64 + n*16 + l15)*64 + ks*32 + lg*8];
            #pragma unroll
            for (int m = 0; m < 4; ++m)
                #pragma unroll
                for (int n = 0; n < 4; ++n)
                    acc[m][n] = __builtin_amdgcn_mfma_f32_16x16x32_bf16(a[m], b[n], acc[m][n], 0, 0, 0);
        }
        __syncthreads();
    }

    const bool isK = wn < 2;
    bf16* tile = isK ? KT : VT;
    #pragma unroll
    for (int m = 0; m < 4; ++m) {
        #pragma unroll
        for (int n = 0; n < 4; ++n) {
            #pragma unroll
            for (int r = 0; r < 4; ++r) {
                const int row = wm * 64 + m * 16 + lg * 4 + r;
                const int col = (wn & 1) * 64 + n * 16 + l15;
                float v = acc[m][n][r];
                if (isK) v = v > 0.f ? v + 1.f : __expf(v);
                else     v *= escale;
                tile[row * 128 + col] = __float2bfloat16(v);
            }
        }
    }
    __syncthreads();

    const int h_l = t >> 7;
    const int d   = (t & 127) >> 2;
    const int vg  = t & 3;
    float a2[8] = {};
    float ks = 0.f;
    #pragma unroll 4
    for (int row = 0; row < 128; ++row) {
        const float kd = __bfloat162float(KT[row * 128 + h_l * 32 + d]);
        ks += kd;
        const short8 vv = *(const short8*)&VT[row * 128 + h_l * 32 + vg * 8];
        #pragma unroll
        for (int u = 0; u < 8; ++u) a2[u] += kd * b2f(vv[u]);
    }
    short8 o;
    #pragma unroll
    for (int u = 0; u < 8; ++u) o[u] = f2b(a2[u]);
    *(short8*)&partKV[(long)cid * 8192 + (hh * 4 + h_l) * 1024 + d * 32 + vg * 8] = o;
    if (vg == 0) partKs[cid * 256 + (hh * 4 + h_l) * 32 + d] = ks;
}

// ---------------------------------------------------------------------------
// MERGED KV reduce: 256 cid partials -> KVaug bf16 [n][h][32][48] in ONE
// kernel (single-stage fp32 accumulation; better rounding than 2-stage).
// Grid 32 = (n<<3)|h.
// ---------------------------------------------------------------------------
__global__ __launch_bounds__(256)
void k_kvred(const bf16* __restrict__ partKV, const float* __restrict__ partKs,
             bf16* __restrict__ KVb)
{
    const int bk = blockIdx.x;
    const int n = bk >> 3, h = bk & 7;
    const int t = threadIdx.x;
    const int d = t >> 3, vg = t & 7;
    float s[4] = {};
    #pragma unroll 8
    for (int i = 0; i < 64; ++i) {
        const int cid = n * 64 + i;
        const bf16x4 p = *(const bf16x4*)&partKV[(long)cid * 8192 + h * 1024 + d * 32 + vg * 4];
        #pragma unroll
        for (int j = 0; j < 4; ++j) s[j] += b2f(p[j]);
    }
    bf16* dst = KVb + ((long)n * 8 + h) * 1536 + d * 48;
    bf16x4 o;
    #pragma unroll
    for (int j = 0; j < 4; ++j) o[j] = f2b(s[j]);
    *(bf16x4*)&dst[vg * 4] = o;
    if (vg == 0) {
        float ks = 0.f;
        #pragma unroll 8
        for (int i = 0; i < 64; ++i) {
            const int cid = n * 64 + i;
            ks += partKs[cid * 256 + h * 32 + d];
        }
        short8 z0 = {};
        z0[0] = f2b(ks);
        *(short8*)&dst[32] = z0;
        short8 zz = {};
        *(short8*)&dst[40] = zz;
    }
}

// ---------------------------------------------------------------------------
// MEGA v2: Q-proj + fmap + attention + merge-GEMM + LN1 with PIPELINED
// staging. Triple-buffered A/B tiles (3 bufs kill the cross-wave
// read/write-same-region hazard of depth-2 dbuf), counted vmcnt (5/tile
// GEMM1, 4/tile GEMM2; never 0 mid-loop), raw s_barrier (no vm drain).
// GEMM2's WmT tiles pre-issued BEFORE attn; KVb loads issued BEFORE those
// stages so the compiler's KVb wait leaves the stages in flight.
// LDS: A 3x8K + B 3x32K + QM 33K + ln 2K = 155 KB -> 1 block/CU.
// Math identical to proven R8 k_qaml.
// ---------------------------------------------------------------------------
__global__ __launch_bounds__(512)
void k_qaml(const bf16* __restrict__ xb, const bf16* __restrict__ WqT,
            const bf16* __restrict__ WmT, const bf16* __restrict__ KVb,
            const float* __restrict__ g, const float* __restrict__ b,
            bf16* __restrict__ msgln)
{
    __shared__ __attribute__((aligned(16))) bf16 A3[3][4096];
    __shared__ __attribute__((aligned(16))) bf16 B3[3][16384];
    __shared__ __attribute__((aligned(16))) bf16 QM[64 * 264];
    __shared__ float lnS[4][64];
    __shared__ float lnQ[4][64];
    const int t = threadIdx.x, w = t >> 6, lane = t & 63;
    const int wm = w >> 2, wn = w & 3;
    const long row0 = (long)blockIdx.x * 64;
    const int n_b = (int)(row0 >> 13);
    const int lr = lane >> 3, lc = (lane & 7) * 8;
    const int lg = lane >> 4, l15 = lane & 15;

    auto stage1 = [&](int kti, int buf) {        // GEMM1 tile: 5 loads/thread
        const int kt = kti * 64;
        async16(xb + (row0 + w * 8 + lr) * 256 + kt + lc, &A3[buf][w * 512]);
        #pragma unroll
        for (int i = 0; i < 4; ++i) {
            const int ch = i * 8 + w;
            async16(WqT + (long)(ch * 8 + lr) * 256 + kt + lc, &B3[buf][ch * 512]);
        }
    };
    auto stage2 = [&](int kti, int buf) {        // GEMM2 B tile: 4 loads/thread
        const int kt = kti * 64;
        #pragma unroll
        for (int i = 0; i < 4; ++i) {
            const int ch = i * 8 + w;
            async16(WmT + (long)(ch * 8 + lr) * 256 + kt + lc, &B3[buf][ch * 512]);
        }
    };

    // ================= GEMM1: Q = fmap(x @ Wq), pipelined =================
    f32x4 acc1[2][4] = {};
    stage1(0, 0); stage1(1, 1);
    asm volatile("s_waitcnt vmcnt(5)" ::: "memory");   // tile0 landed
    __builtin_amdgcn_s_barrier();

    #pragma unroll
    for (int tt = 0; tt < 4; ++tt) {
        const int buf = tt % 3;            // t0:0 t1:1 t2:2 t3:0
        short8 a[2][2], bb[2][4];
        #pragma unroll
        for (int ks = 0; ks < 2; ++ks) {
            #pragma unroll
            for (int m = 0; m < 2; ++m)
                a[ks][m] = *(const short8*)&A3[buf][(wm*32 + m*16 + l15)*64 + ks*32 + lg*8];
            #pragma unroll
            for (int n = 0; n < 4; ++n)
                bb[ks][n] = *(const short8*)&B3[buf][(wn*64 + n*16 + l15)*64 + ks*32 + lg*8];
        }
        if (tt < 2) stage1(tt + 2, (tt + 2) % 3);   // into retired buffer
        #pragma unroll
        for (int ks = 0; ks < 2; ++ks)
            #pragma unroll
            for (int m = 0; m < 2; ++m)
                #pragma unroll
                for (int n = 0; n < 4; ++n)
                    acc1[m][n] = __builtin_amdgcn_mfma_f32_16x16x32_bf16(a[ks][m], bb[ks][n], acc1[m][n], 0, 0, 0);
        if (tt < 2)       asm volatile("s_waitcnt vmcnt(5)" ::: "memory");
        else if (tt == 2) asm volatile("s_waitcnt vmcnt(0)" ::: "memory");
        __builtin_amdgcn_s_barrier();
    }

    // fmap -> QM
    #pragma unroll
    for (int m = 0; m < 2; ++m) {
        #pragma unroll
        for (int n = 0; n < 4; ++n) {
            #pragma unroll
            for (int r = 0; r < 4; ++r) {
                const int row = wm * 32 + m * 16 + lg * 4 + r;
                const int col = wn * 64 + n * 16 + l15;
                float v = acc1[m][n][r];
                v = v > 0.f ? v + 1.f : __expf(v);
                QM[row * 264 + col] = __float2bfloat16(v);
            }
        }
    }

    // KVb loads (BEFORE stage2 so the compiler's wait keeps stages in flight)
    const bf16* kvh = KVb + (long)n_b * 12288 + w * 1536;
    short8 kb0, kb1, kbz;
    #pragma unroll
    for (int j = 0; j < 8; ++j) {
        const int drow = (lg * 8 + j) * 48;
        kb0[j] = __builtin_bit_cast(short, kvh[drow + l15]);
        kb1[j] = __builtin_bit_cast(short, kvh[drow + 16 + l15]);
        kbz[j] = __builtin_bit_cast(short, kvh[drow + 32 + l15]);
    }

    // pre-issue GEMM2 tiles 0,1 (bufs 1,2 retired since GEMM1 t=1/t=2 bars)
    stage2(0, 1); stage2(1, 2);

    asm volatile("s_waitcnt lgkmcnt(0)" ::: "memory");  // QM writes visible
    __builtin_amdgcn_sched_barrier(0);
    __builtin_amdgcn_s_barrier();

    // ================= attention: wave w = head w =================
    {
        f32x4 ra0[4], ra1[4];
        #pragma unroll
        for (int m2 = 0; m2 < 4; ++m2) {
            const short8 a = *(const short8*)&QM[(m2 * 16 + l15) * 264 + w * 32 + lg * 8];
            f32x4 a0 = {}, a1 = {}, az = {};
            a0 = __builtin_amdgcn_mfma_f32_16x16x32_bf16(a, kb0, a0, 0, 0, 0);
            a1 = __builtin_amdgcn_mfma_f32_16x16x32_bf16(a, kb1, a1, 0, 0, 0);
            az = __builtin_amdgcn_mfma_f32_16x16x32_bf16(a, kbz, az, 0, 0, 0);
            #pragma unroll
            for (int r = 0; r < 4; ++r) {
                const float z   = __shfl(az[r], lane & 48);
                const float inv = 8192.f / (z + EPS_ATTN);
                ra0[m2][r] = a0[r] * inv;
                ra1[m2][r] = a1[r] * inv;
            }
        }
        // Q reads retired before overwrite (same-wave cols; lgkm orders)
        asm volatile("s_waitcnt lgkmcnt(0)" ::: "memory");
        __builtin_amdgcn_sched_barrier(0);
        __builtin_amdgcn_s_barrier();
        #pragma unroll
        for (int m2 = 0; m2 < 4; ++m2) {
            #pragma unroll
            for (int r = 0; r < 4; ++r) {
                const int row = m2 * 16 + lg * 4 + r;
                QM[row * 264 + w * 32 + l15]      = __float2bfloat16(ra0[m2][r]);
                QM[row * 264 + w * 32 + 16 + l15] = __float2bfloat16(ra1[m2][r]);
            }
        }
    }
    asm volatile("s_waitcnt lgkmcnt(0)" ::: "memory");  // msg writes visible
    __builtin_amdgcn_sched_barrier(0);
    __builtin_amdgcn_s_barrier();

    // ================= GEMM2: msgln = LN1(msg @ Wm), pipelined ===========
    asm volatile("s_waitcnt vmcnt(4)" ::: "memory");    // G2 tile0 landed
    __builtin_amdgcn_s_barrier();

    f32x4 acc2[2][4] = {};
    #pragma unroll
    for (int tt = 0; tt < 4; ++tt) {
        const int buf = (tt + 1) % 3;      // t0:1 t1:2 t2:0 t3:1
        short8 a[2][2], bb[2][4];
        #pragma unroll
        for (int ks = 0; ks < 2; ++ks) {
            #pragma unroll
            for (int m = 0; m < 2; ++m)
                a[ks][m] = *(const short8*)&QM[(wm*32 + m*16 + l15) * 264 + tt*64 + ks*32 + lg*8];
            #pragma unroll
            for (int n = 0; n < 4; ++n)
                bb[ks][n] = *(const short8*)&B3[buf][(wn*64 + n*16 + l15)*64 + ks*32 + lg*8];
        }
        if (tt < 2) stage2(tt + 2, (tt + 3) % 3);  // t0: tile2->b0; t1: tile3->b1
        #pragma unroll
        for (int ks = 0; ks < 2; ++ks)
            #pragma unroll
            for (int m = 0; m < 2; ++m)
                #pragma unroll
                for (int n = 0; n < 4; ++n)
                    acc2[m][n] = __builtin_amdgcn_mfma_f32_16x16x32_bf16(a[ks][m], bb[ks][n], acc2[m][n], 0, 0, 0);
        if (tt < 2)       asm volatile("s_waitcnt vmcnt(4)" ::: "memory");
        else if (tt == 2) asm volatile("s_waitcnt vmcnt(0)" ::: "memory");
        __builtin_amdgcn_s_barrier();
    }

    // LN1 epilogue (proven)
    #pragma unroll
    for (int m = 0; m < 2; ++m) {
        #pragma unroll
        for (int r = 0; r < 4; ++r) {
            float ls = 0.f, lq = 0.f;
            #pragma unroll
            for (int n = 0; n < 4; ++n) {
                const float v = acc2[m][n][r];
                ls += v; lq += v * v;
            }
            #pragma unroll
            for (int o = 1; o < 16; o <<= 1) {
                ls += __shfl_xor(ls, o);
                lq += __shfl_xor(lq, o);
            }
            if (l15 == 0) {
                const int row = wm * 32 + m * 16 + lg * 4 + r;
                lnS[wn][row] = ls;
                lnQ[wn][row] = lq;
            }
        }
    }
    __syncthreads();

    float gv[4], bv[4];
    #pragma unroll
    for (int n = 0; n < 4; ++n) {
        const int col = wn * 64 + n * 16 + l15;
        gv[n] = g[col]; bv[n] = b[col];
    }
    #pragma unroll
    for (int m = 0; m < 2; ++m) {
        #pragma unroll
        for (int r = 0; r < 4; ++r) {
            const int row = wm * 32 + m * 16 + lg * 4 + r;
            const float S  = lnS[0][row] + lnS[1][row] + lnS[2][row] + lnS[3][row];
            const float Qq = lnQ[0][row] + lnQ[1][row] + lnQ[2][row] + lnQ[3][row];
            const float mean = S * (1.f / 256.f);
            const float var  = Qq * (1.f / 256.f) - mean * mean;
            const float rstd = rsqrtf(var + EPS_LN);
            const long grow = row0 + row;
            #pragma unroll
            for (int n = 0; n < 4; ++n) {
                const int col = wn * 64 + n * 16 + l15;
                const float y = (acc2[m][n][r] - mean) * rstd * gv[n] + bv[n];
                msgln[grow * 256 + col] = __float2bfloat16(y);
            }
        }
    }
}

// ---------------------------------------------------------------------------
// W1 GEMM, 8-PHASE 256x256 schedule (proven in R11). t = relu([A0|A1] @ W1).
// ---------------------------------------------------------------------------
__global__ __launch_bounds__(512, 2)
void k_gemmW1_8p(const bf16* __restrict__ A0, const bf16* __restrict__ A1,
                 const bf16* __restrict__ BT, bf16* __restrict__ C)
{
    __shared__ __attribute__((aligned(16))) bf16 S[65536];   // 128 KB
    const int t = threadIdx.x, w = t >> 6, lane = t & 63;
    const int wm = w >> 2, wn = w & 3;
    const int lg = lane >> 4, l15 = lane & 15;
    const int orig = blockIdx.y * gridDim.x + blockIdx.x;    // 0..255
    const int swz  = (orig & 7) * 32 + (orig >> 3);          // bijective XCD
    const long row0 = (long)(swz >> 1) * 256;
    const long col0 = (long)(swz & 1) * 256;

    f32x4 acc[8][4] = {};
    short8 av[4], bv0[4], bv1[4];

    auto stageA = [&](int tile, int half) {
        if (tile >= 8) return;
        const bf16* Asrc = (tile < 4) ? A0 : A1;
        const int kbase = (tile & 3) * 64;
        #pragma unroll
        for (int i = 0; i < 2; ++i) {
            const int cbase = i * 512 + w * 64;
            const int c = cbase + lane;
            const int srow = c >> 3;
            const int lcol = 8 * ((c & 7) ^ (srow & 7));
            async16(Asrc + (row0 + half * 128 + srow) * 256 + kbase + lcol,
                    &S[(tile & 1) * 32768 + half * 8192 + cbase * 8]);
        }
    };
    auto stageB = [&](int tile, int half) {
        if (tile >= 8) return;
        const int kbase = tile * 64;
        #pragma unroll
        for (int i = 0; i < 2; ++i) {
            const int cbase = i * 512 + w * 64;
            const int c = cbase + lane;
            const int srow = c >> 3;
            const int lcol = 8 * ((c & 7) ^ (srow & 7));
            async16(BT + (col0 + half * 128 + srow) * 512 + kbase + lcol,
                    &S[(tile & 1) * 32768 + 16384 + half * 8192 + cbase * 8]);
        }
    };

#define RD_A(BUF, MH, KS) do { _Pragma("unroll")                               \
    for (int m_ = 0; m_ < 4; ++m_) {                                           \
        const int row_ = wm * 128 + (MH) * 64 + m_ * 16 + l15;                 \
        av[m_] = *(const short8*)&S[(BUF) * 32768 + row_ * 64 +                \
                 (((KS) * 32 + lg * 8) ^ ((row_ & 7) << 3))]; } } while (0)

#define RD_B(BUF, KS, BV) do { _Pragma("unroll")                               \
    for (int n_ = 0; n_ < 4; ++n_) {                                           \
        const int row_ = wn * 64 + n_ * 16 + l15;                              \
        (BV)[n_] = *(const short8*)&S[(BUF) * 32768 + 16384 + row_ * 64 +      \
                 (((KS) * 32 + lg * 8) ^ ((row_ & 7) << 3))]; } } while (0)

#define DO_MFMA(MH, BV) do { __builtin_amdgcn_s_setprio(1); _Pragma("unroll")  \
    for (int m_ = 0; m_ < 4; ++m_) { _Pragma("unroll")                         \
        for (int n_ = 0; n_ < 4; ++n_)                                         \
            acc[(MH) * 4 + m_][n_] = __builtin_amdgcn_mfma_f32_16x16x32_bf16(  \
                av[m_], (BV)[n_], acc[(MH) * 4 + m_][n_], 0, 0, 0); }          \
    __builtin_amdgcn_s_setprio(0); } while (0)

#define BAR() __builtin_amdgcn_s_barrier()

    stageB(0, 0); stageB(0, 1); stageA(0, 0); stageA(0, 1);
    stageB(1, 0); stageB(1, 1);
    asm volatile("s_waitcnt vmcnt(4)" ::: "memory");
    BAR();

    for (int it = 0; it < 4; ++it) {
        const int T1 = 2 * it + 1;
        RD_B(0, 0, bv0); RD_A(0, 0, 0); stageA(T1, 0);
        BAR(); DO_MFMA(0, bv0); BAR();
        RD_B(0, 1, bv1); RD_A(0, 0, 1); stageA(T1, 1);
        BAR(); DO_MFMA(0, bv1); BAR();
        RD_A(0, 1, 0); stageB(T1 + 1, 0);
        BAR(); DO_MFMA(1, bv0); BAR();
        RD_A(0, 1, 1); stageB(T1 + 1, 1);
        BAR(); DO_MFMA(1, bv1);
        if (it == 3) asm volatile("s_waitcnt vmcnt(0)" ::: "memory");
        else         asm volatile("s_waitcnt vmcnt(4)" ::: "memory");
        BAR();
        RD_B(1, 0, bv0); RD_A(1, 0, 0); stageA(T1 + 1, 0);
        BAR(); DO_MFMA(0, bv0); BAR();
        RD_B(1, 1, bv1); RD_A(1, 0, 1); stageA(T1 + 1, 1);
        BAR(); DO_MFMA(0, bv1); BAR();
        RD_A(1, 1, 0); stageB(T1 + 2, 0);
        BAR(); DO_MFMA(1, bv0); BAR();
        RD_A(1, 1, 1); stageB(T1 + 2, 1);
        BAR(); DO_MFMA(1, bv1);
        if (it < 3) asm volatile("s_waitcnt vmcnt(4)" ::: "memory");
        BAR();
    }

    #pragma unroll
    for (int mi = 0; mi < 8; ++mi) {
        #pragma unroll
        for (int n = 0; n < 4; ++n) {
            #pragma unroll
            for (int r = 0; r < 4; ++r) {
                const long row = row0 + wm * 128 + mi * 16 + lg * 4 + r;
                const long col = col0 + wn * 64 + n * 16 + l15;
                const float v = acc[mi][n][r];
                C[row * 512 + col] = __float2bfloat16(v > 0.f ? v : 0.f);
            }
        }
    }
#undef RD_A
#undef RD_B
#undef DO_MFMA
#undef BAR
}

// ---------------------------------------------------------------------------
// W2 GEMM + LN2 + residual, 8-PHASE 256x256 schedule (proven R12-neutral,
// kept: at memory floor).
// ---------------------------------------------------------------------------
__global__ __launch_bounds__(512, 2)
void k_ln2_8p(const bf16* __restrict__ A, const bf16* __restrict__ BT,
              const float* __restrict__ g, const float* __restrict__ b,
              const float* __restrict__ xres, float* __restrict__ out)
{
    __shared__ __attribute__((aligned(16))) bf16 S[65536];   // 128 KB
    const int t = threadIdx.x, w = t >> 6, lane = t & 63;
    const int wm = w >> 2, wn = w & 3;
    const int lg = lane >> 4, l15 = lane & 15;
    const int orig = blockIdx.x;                             // 0..127
    const int swz  = (orig & 7) * 16 + (orig >> 3);          // bijective XCD
    const long row0 = (long)swz * 256;

    f32x4 acc[8][4] = {};
    short8 av[4], bv0[4], bv1[4];

    auto stageA = [&](int tile, int half) {
        if (tile >= 8) return;
        const int kbase = tile * 64;
        #pragma unroll
        for (int i = 0; i < 2; ++i) {
            const int cbase = i * 512 + w * 64;
            const int c = cbase + lane;
            const int srow = c >> 3;
            const int lcol = 8 * ((c & 7) ^ (srow & 7));
            async16(A + (row0 + half * 128 + srow) * 512 + kbase + lcol,
                    &S[(tile & 1) * 32768 + half * 8192 + cbase * 8]);
        }
    };
    auto stageB = [&](int tile, int half) {
        if (tile >= 8) return;
        const int kbase = tile * 64;
        #pragma unroll
        for (int i = 0; i < 2; ++i) {
            const int cbase = i * 512 + w * 64;
            const int c = cbase + lane;
            const int srow = c >> 3;
            const int lcol = 8 * ((c & 7) ^ (srow & 7));
            async16(BT + (long)(half * 128 + srow) * 512 + kbase + lcol,
                    &S[(tile & 1) * 32768 + 16384 + half * 8192 + cbase * 8]);
        }
    };

#define RD_A(BUF, MH, KS) do { _Pragma("unroll")                               \
    for (int m_ = 0; m_ < 4; ++m_) {                                           \
        const int row_ = wm * 128 + (MH) * 64 + m_ * 16 + l15;                 \
        av[m_] = *(const short8*)&S[(BUF) * 32768 + row_ * 64 +                \
                 (((KS) * 32 + lg * 8) ^ ((row_ & 7) << 3))]; } } while (0)

#define RD_B(BUF, KS, BV) do { _Pragma("unroll")                               \
    for (int n_ = 0; n_ < 4; ++n_) {                                           \
        const int row_ = wn * 64 + n_ * 16 + l15;                              \
        (BV)[n_] = *(const short8*)&S[(BUF) * 32768 + 16384 + row_ * 64 +      \
                 (((KS) * 32 + lg * 8) ^ ((row_ & 7) << 3))]; } } while (0)

#define DO_MFMA(MH, BV) do { __builtin_amdgcn_s_setprio(1); _Pragma("unroll")  \
    for (int m_ = 0; m_ < 4; ++m_) { _Pragma("unroll")                         \
        for (int n_ = 0; n_ < 4; ++n_)                                         \
            acc[(MH) * 4 + m_][n_] = __builtin_amdgcn_mfma_f32_16x16x32_bf16(  \
                av[m_], (BV)[n_], acc[(MH) * 4 + m_][n_], 0, 0, 0); }          \
    __builtin_amdgcn_s_setprio(0); } while (0)

#define BAR() __builtin_amdgcn_s_barrier()

    stageB(0, 0); stageB(0, 1); stageA(0, 0); stageA(0, 1);
    stageB(1, 0); stageB(1, 1);
    asm volatile("s_waitcnt vmcnt(4)" ::: "memory");
    BAR();

    for (int it = 0; it < 4; ++it) {
        const int T1 = 2 * it + 1;
        RD_B(0, 0, bv0); RD_A(0, 0, 0); stageA(T1, 0);
        BAR(); DO_MFMA(0, bv0); BAR();
        RD_B(0, 1, bv1); RD_A(0, 0, 1); stageA(T1, 1);
        BAR(); DO_MFMA(0, bv1); BAR();
        RD_A(0, 1, 0); stageB(T1 + 1, 0);
        BAR(); DO_MFMA(1, bv0); BAR();
        RD_A(0, 1, 1); stageB(T1 + 1, 1);
        BAR(); DO_MFMA(1, bv1);
        if (it == 3) asm volatile("s_waitcnt vmcnt(0)" ::: "memory");
        else         asm volatile("s_waitcnt vmcnt(4)" ::: "memory");
        BAR();
        RD_B(1, 0, bv0); RD_A(1, 0, 0); stageA(T1 + 1, 0);
        BAR(); DO_MFMA(0, bv0); BAR();
        RD_B(1, 1, bv1); RD_A(1, 0, 1); stageA(T1 + 1, 1);
        BAR(); DO_MFMA(0, bv1); BAR();
        RD_A(1, 1, 0); stageB(T1 + 2, 0);
        BAR(); DO_MFMA(1, bv0); BAR();
        RD_A(1, 1, 1); stageB(T1 + 2, 1);
        BAR(); DO_MFMA(1, bv1);
        if (it < 3) asm volatile("s_waitcnt vmcnt(4)" ::: "memory");
        BAR();
    }

    __syncthreads();
    float* lnS = (float*)S;
    float* lnQ = (float*)((char*)S + 4096);

    #pragma unroll
    for (int mi = 0; mi < 8; ++mi) {
        #pragma unroll
        for (int r = 0; r < 4; ++r) {
            float ls = 0.f, lq = 0.f;
            #pragma unroll
            for (int n = 0; n < 4; ++n) {
                const float v = acc[mi][n][r];
                ls += v; lq += v * v;
            }
            #pragma unroll
            for (int o = 1; o < 16; o <<= 1) {
                ls += __shfl_xor(ls, o);
                lq += __shfl_xor(lq, o);
            }
            if (l15 == 0) {
                const int row = wm * 128 + mi * 16 + lg * 4 + r;
                lnS[wn * 256 + row] = ls;
                lnQ[wn * 256 + row] = lq;
            }
        }
    }
    __syncthreads();

    float gv[4], bv[4];
    #pragma unroll
    for (int n = 0; n < 4; ++n) {
        const int col = wn * 64 + n * 16 + l15;
        gv[n] = g[col]; bv[n] = b[col];
    }
    #pragma unroll
    for (int mi = 0; mi < 8; ++mi) {
        #pragma unroll
        for (int r = 0; r < 4; ++r) {
            const int row = wm * 128 + mi * 16 + lg * 4 + r;
            const float Sm = lnS[row] + lnS[256 + row] + lnS[512 + row] + lnS[768 + row];
            const float Qq = lnQ[row] + lnQ[256 + row] + lnQ[512 + row] + lnQ[768 + row];
            const float mean = Sm * (1.f / 256.f);
            const float var  = Qq * (1.f / 256.f) - mean * mean;
            const float rstd = rsqrtf(var + EPS_LN);
            const long grow = row0 + row;
            #pragma unroll
            for (int n = 0; n < 4; ++n) {
                const int col = wn * 64 + n * 16 + l15;
                const float y = (acc[mi][n][r] - mean) * rstd * gv[n] + bv[n];
                out[grow * 256 + col] = xres[grow * 256 + col] + y;
            }
        }
    }
#undef RD_A
#undef RD_B
#undef DO_MFMA
#undef BAR
}

// ---------------------------------------------------------------------------
extern "C" void kernel_launch(void* const* d_in, const int* in_sizes, int n_in,
                              void* d_out, int out_size, void* d_ws, size_t ws_size,
                              hipStream_t stream)
{
    const float* x      = (const float*)d_in[0];
    const float* source = (const float*)d_in[1];
    const float* Wq     = (const float*)d_in[2];
    const float* Wk     = (const float*)d_in[3];
    const float* Wv     = (const float*)d_in[4];
    const float* Wm     = (const float*)d_in[5];
    const float* W1     = (const float*)d_in[6];
    const float* W2     = (const float*)d_in[7];
    const float* g1     = (const float*)d_in[8];
    const float* b1     = (const float*)d_in[9];
    const float* g2     = (const float*)d_in[10];
    const float* b2     = (const float*)d_in[11];
    float* out = (float*)d_out;

    const size_t U = 32768ull * 256ull;
    char* w = (char*)d_ws;

    bf16* x_bf  = (bf16*)(w + 0 * U * 2);
    bf16* s_bf  = (bf16*)(w + 1 * U * 2);
    bf16* msgln = (bf16*)(w + 2 * U * 2);
    bf16* t_bf  = (bf16*)(w + 3 * U * 2);   // slots 3-4 ([32768,512])

    char* wx = w + 7 * U * 2;
    bf16* WqT = (bf16*)wx; wx += 65536 * 2;
    bf16* WkT = (bf16*)wx; wx += 65536 * 2;   // contiguous with WvT
    bf16* WvT = (bf16*)wx; wx += 65536 * 2;
    bf16* WmT = (bf16*)wx; wx += 65536 * 2;
    bf16* W1T = (bf16*)wx; wx += 262144 * 2;
    bf16* W2T = (bf16*)wx; wx += 131072 * 2;
    bf16* partKV = (bf16*)wx; wx += 2097152 * 2;   // 256 cid x 8192
    float* partKs = (float*)wx; wx += 65536 * 4;   // 256 cid x 256
    bf16* KVb    = (bf16*)wx; wx += 49152 * 2;     // [n][h][32][48]

    const dim3 blk(256);

    // 1) prep
    k_prep<<<8352, blk, 0, stream>>>(x, source, x_bf, s_bf,
                                     Wq, Wk, Wv, Wm, W1, W2,
                                     WqT, WkT, WvT, WmT, W1T, W2T);

    // 2) fused K/V projection + partial KV/Ksum
    k_kvproj<<<dim3(256, 2), dim3(512), 0, stream>>>(s_bf, WkT, partKV, partKs,
                                                     1.f / 8192.f);

    // 3) merged reduce -> KVaug
    k_kvred<<<32, blk, 0, stream>>>(partKV, partKs, KVb);

    // 4) MEGA v2 (pipelined): Q-proj + attn + merge + LN1 -> msgln
    k_qaml<<<512, dim3(512), 0, stream>>>(x_bf, WqT, WmT, KVb, g1, b1, msgln);

    // 5) MLP: 8-phase W1; 8-phase W2+LN2+residual
    k_gemmW1_8p<<<dim3(128, 2), dim3(512), 0, stream>>>(x_bf, msgln, W1T, t_bf);
    k_ln2_8p<<<128, dim3(512), 0, stream>>>(t_bf, W2T, g2, b2, x, out);
}

// Round 14
// 130.926 us; speedup vs baseline: 1.0443x; 1.0443x over previous
//
#include <hip/hip_runtime.h>
#include <hip/hip_bf16.h>
#include <stdint.h>

typedef __hip_bfloat16 bf16;
typedef __attribute__((ext_vector_type(8))) short short8;
typedef __attribute__((ext_vector_type(4))) short bf16x4;
typedef __attribute__((ext_vector_type(4))) float f32x4;

#define EPS_ATTN 1e-6f
#define EPS_LN   1e-5f

__device__ __forceinline__ float b2f(short s) {
    return __builtin_bit_cast(float, (unsigned)((unsigned short)s) << 16);
}
__device__ __forceinline__ short f2b(float f) {
    return __builtin_bit_cast(short, __float2bfloat16(f));
}

// ---------------------------------------------------------------------------
// async global->LDS, 16B per lane. LDS dest = wave-uniform base + lane*16.
// ---------------------------------------------------------------------------
__device__ __forceinline__ void async16(const void* g, void* l) {
    __builtin_amdgcn_global_load_lds(
        (const __attribute__((address_space(1))) void*)g,
        (__attribute__((address_space(3))) void*)l,
        16, 0, 0);
}

// ---------------------------------------------------------------------------
// Prep: fp32->bf16 converts (x, source) + all 6 weight transposes, ONE launch.
// ---------------------------------------------------------------------------
__global__ __launch_bounds__(256)
void k_prep(const float* __restrict__ x, const float* __restrict__ src,
            bf16* __restrict__ x_bf, bf16* __restrict__ s_bf,
            const float* __restrict__ Wq, const float* __restrict__ Wk,
            const float* __restrict__ Wv, const float* __restrict__ Wm,
            const float* __restrict__ W1, const float* __restrict__ W2,
            bf16* __restrict__ WqT, bf16* __restrict__ WkT,
            bf16* __restrict__ WvT, bf16* __restrict__ WmT,
            bf16* __restrict__ W1T, bf16* __restrict__ W2T)
{
    __shared__ float tile[64][65];
    const int blk = blockIdx.x;
    if (blk < 8192) {
        const float* in = (blk < 4096) ? x : src;
        bf16* out       = (blk < 4096) ? x_bf : s_bf;
        const long id = (long)(blk & 4095) * 256 + threadIdx.x;
        const float4 a = ((const float4*)in)[id * 2];
        const float4 b = ((const float4*)in)[id * 2 + 1];
        short8 o;
        o[0] = f2b(a.x); o[1] = f2b(a.y); o[2] = f2b(a.z); o[3] = f2b(a.w);
        o[4] = f2b(b.x); o[5] = f2b(b.y); o[6] = f2b(b.z); o[7] = f2b(b.w);
        ((short8*)out)[id] = o;
        return;
    }
    const int b = blk - 8192;
    const float* W; bf16* WT; int K, N, local;
    if      (b < 16)  { W = Wq; WT = WqT; K = 256; N = 256; local = b; }
    else if (b < 32)  { W = Wk; WT = WkT; K = 256; N = 256; local = b - 16; }
    else if (b < 48)  { W = Wv; WT = WvT; K = 256; N = 256; local = b - 32; }
    else if (b < 64)  { W = Wm; WT = WmT; K = 256; N = 256; local = b - 48; }
    else if (b < 128) { W = W1; WT = W1T; K = 512; N = 512; local = b - 64; }
    else              { W = W2; WT = W2T; K = 512; N = 256; local = b - 128; }
    const int tk = K / 64;
    const int k0 = (local % tk) * 64, n0 = (local / tk) * 64;
    const int ty = threadIdx.x >> 4, tx = threadIdx.x & 15;
    #pragma unroll
    for (int i = 0; i < 4; ++i) {
        const int k = ty + i * 16;
        const float4 v = *(const float4*)&W[(long)(k0 + k) * N + n0 + tx * 4];
        tile[k][tx * 4 + 0] = v.x; tile[k][tx * 4 + 1] = v.y;
        tile[k][tx * 4 + 2] = v.z; tile[k][tx * 4 + 3] = v.w;
    }
    __syncthreads();
    #pragma unroll
    for (int i = 0; i < 4; ++i) {
        const int n = ty + i * 16;
        bf16x4 o;
        #pragma unroll
        for (int j = 0; j < 4; ++j) o[j] = f2b(tile[tx * 4 + j][n]);
        *(bf16x4*)&WT[(long)(n0 + n) * K + k0 + tx * 4] = o;
    }
}

// ---------------------------------------------------------------------------
// FUSED K/V projection + feature-map + partial-KV/Ksum (proven in R9).
// ---------------------------------------------------------------------------
__global__ __launch_bounds__(512)
void k_kvproj(const bf16* __restrict__ A, const bf16* __restrict__ BT,
              bf16* __restrict__ partKV, float* __restrict__ partKs,
              float escale)
{
    __shared__ __attribute__((aligned(16))) bf16 S[32768];   // 64 KB union
    bf16* Asm = S;
    bf16* Bsm = S + 8192;
    bf16* KT  = S;
    bf16* VT  = S + 16384;

    const int t = threadIdx.x, w = t >> 6, lane = t & 63;
    const int wm = w >> 2, wn = w & 3;
    const int flat = blockIdx.y * gridDim.x + blockIdx.x;   // 0..511
    const int swz  = (flat & 7) * 64 + (flat >> 3);         // bijective, XCD
    const int cid  = swz >> 1;
    const int hh   = swz & 1;
    const long row0 = (long)cid * 128;
    const int lr = lane >> 3, lc = (lane & 7) * 8;
    const int lg = lane >> 4, l15 = lane & 15;

    f32x4 acc[4][4] = {};

    for (int kt = 0; kt < 256; kt += 64) {
        #pragma unroll
        for (int i = 0; i < 2; ++i) {
            const int g = w * 2 + i;
            async16(A + (row0 + g * 8 + lr) * 256 + kt + lc, &Asm[g * 512]);
        }
        #pragma unroll
        for (int i = 0; i < 4; ++i) {
            const int g = w * 4 + i;
            const long brow = (g < 16)
                ? (long)(hh * 128 + g * 8 + lr)
                : (long)(256 + hh * 128 + (g - 16) * 8 + lr);
            async16(BT + brow * 256 + kt + lc, &Bsm[g * 512]);
        }
        __syncthreads();
        #pragma unroll
        for (int ks = 0; ks < 2; ++ks) {
            short8 a[4], b[4];
            #pragma unroll
            for (int m = 0; m < 4; ++m)
                a[m] = *(const short8*)&Asm[(wm*64 + m*16 + l15)*64 + ks*32 + lg*8];
            #pragma unroll
            for (int n = 0; n < 4; ++n)
                b[n] = *(const short8*)&Bsm[(wn*64 + n*16 + l15)*64 + ks*32 + lg*8];
            #pragma unroll
            for (int m = 0; m < 4; ++m)
                #pragma unroll
                for (int n = 0; n < 4; ++n)
                    acc[m][n] = __builtin_amdgcn_mfma_f32_16x16x32_bf16(a[m], b[n], acc[m][n], 0, 0, 0);
        }
        __syncthreads();
    }

    const bool isK = wn < 2;
    bf16* tile = isK ? KT : VT;
    #pragma unroll
    for (int m = 0; m < 4; ++m) {
        #pragma unroll
        for (int n = 0; n < 4; ++n) {
            #pragma unroll
            for (int r = 0; r < 4; ++r) {
                const int row = wm * 64 + m * 16 + lg * 4 + r;
                const int col = (wn & 1) * 64 + n * 16 + l15;
                float v = acc[m][n][r];
                if (isK) v = v > 0.f ? v + 1.f : __expf(v);
                else     v *= escale;
                tile[row * 128 + col] = __float2bfloat16(v);
            }
        }
    }
    __syncthreads();

    const int h_l = t >> 7;
    const int d   = (t & 127) >> 2;
    const int vg  = t & 3;
    float a2[8] = {};
    float ks = 0.f;
    #pragma unroll 4
    for (int row = 0; row < 128; ++row) {
        const float kd = __bfloat162float(KT[row * 128 + h_l * 32 + d]);
        ks += kd;
        const short8 vv = *(const short8*)&VT[row * 128 + h_l * 32 + vg * 8];
        #pragma unroll
        for (int u = 0; u < 8; ++u) a2[u] += kd * b2f(vv[u]);
    }
    short8 o;
    #pragma unroll
    for (int u = 0; u < 8; ++u) o[u] = f2b(a2[u]);
    *(short8*)&partKV[(long)cid * 8192 + (hh * 4 + h_l) * 1024 + d * 32 + vg * 8] = o;
    if (vg == 0) partKs[cid * 256 + (hh * 4 + h_l) * 32 + d] = ks;
}

// ---------------------------------------------------------------------------
// KV reduce stage 1: 64 chunks/batch -> 8 partials (R12 config).
// ---------------------------------------------------------------------------
__global__ __launch_bounds__(256)
void k_kvred1(const bf16* __restrict__ partKV, const float* __restrict__ partKs,
              bf16* __restrict__ part2, float* __restrict__ part2Ks)
{
    const int bid = blockIdx.x;
    const int c8 = bid & 7, h = (bid >> 3) & 7, n = bid >> 6;
    const int t = threadIdx.x;
    const int d = t >> 3, vg = t & 7;
    float s[4] = {};
    #pragma unroll
    for (int j = 0; j < 8; ++j) {
        const int cid = n * 64 + c8 * 8 + j;
        const bf16x4 p = *(const bf16x4*)&partKV[(long)cid * 8192 + h * 1024 + d * 32 + vg * 4];
        #pragma unroll
        for (int jj = 0; jj < 4; ++jj) s[jj] += b2f(p[jj]);
    }
    bf16x4 o;
    #pragma unroll
    for (int jj = 0; jj < 4; ++jj) o[jj] = f2b(s[jj]);
    *(bf16x4*)&part2[(long)(c8 * 4 + n) * 8192 + h * 1024 + d * 32 + vg * 4] = o;
    if (vg == 0) {
        float ks = 0.f;
        #pragma unroll
        for (int j = 0; j < 8; ++j) {
            const int cid = n * 64 + c8 * 8 + j;
            ks += partKs[cid * 256 + h * 32 + d];
        }
        part2Ks[(c8 * 4 + n) * 256 + h * 32 + d] = ks;
    }
}

// ---------------------------------------------------------------------------
// KV reduce stage 2: 8 partials -> KVaug bf16 [n][h][32][48] (col 32 = Ksum)
// ---------------------------------------------------------------------------
__global__ __launch_bounds__(256)
void k_kvred2(const bf16* __restrict__ part2, const float* __restrict__ part2Ks,
              bf16* __restrict__ KVb)
{
    const int b = blockIdx.x;
    const int n = b >> 3, h = b & 7;
    const int t = threadIdx.x;
    const int d = t >> 3, vg = t & 7;
    float s[4] = {};
    #pragma unroll
    for (int c8 = 0; c8 < 8; ++c8) {
        const bf16x4 p = *(const bf16x4*)&part2[(long)(c8 * 4 + n) * 8192 + h * 1024 + d * 32 + vg * 4];
        #pragma unroll
        for (int j = 0; j < 4; ++j) s[j] += b2f(p[j]);
    }
    bf16* dst = KVb + ((long)n * 8 + h) * 1536 + d * 48;
    bf16x4 o;
    #pragma unroll
    for (int j = 0; j < 4; ++j) o[j] = f2b(s[j]);
    *(bf16x4*)&dst[vg * 4] = o;
    if (vg == 0) {
        float ks = 0.f;
        #pragma unroll
        for (int c8 = 0; c8 < 8; ++c8) ks += part2Ks[(c8 * 4 + n) * 256 + h * 32 + d];
        short8 z0 = {};
        z0[0] = f2b(ks);
        *(short8*)&dst[32] = z0;
        short8 zz = {};
        *(short8*)&dst[40] = zz;
    }
}

// ---------------------------------------------------------------------------
// MEGA: Q-proj + feature-map + attention + merge-GEMM + LN1 (R8/R12 proven
// 2-phase, 2 blocks/CU). ONE change vs R12: GEMM2's first WmT tile is
// pre-issued into Bsm right after GEMM1's final barrier (Bsm dead there),
// hiding its HBM latency under fmap+attention; GEMM2 loop skips kt=0 stage.
// ---------------------------------------------------------------------------
__global__ __launch_bounds__(512)
void k_qaml(const bf16* __restrict__ xb, const bf16* __restrict__ WqT,
            const bf16* __restrict__ WmT, const bf16* __restrict__ KVb,
            const float* __restrict__ g, const float* __restrict__ b,
            bf16* __restrict__ msgln)
{
    __shared__ __attribute__((aligned(16))) bf16 Asm[64 * 64];
    __shared__ __attribute__((aligned(16))) bf16 Bsm[256 * 64];
    __shared__ __attribute__((aligned(16))) bf16 QM[64 * 264];
    __shared__ float lnS[4][64];
    __shared__ float lnQ[4][64];
    const int t = threadIdx.x, w = t >> 6, lane = t & 63;
    const int wm = w >> 2, wn = w & 3;
    const long row0 = (long)blockIdx.x * 64;
    const int n_b = (int)(row0 >> 13);
    const int lr = lane >> 3, lc = (lane & 7) * 8;
    const int lg = lane >> 4, l15 = lane & 15;

    {
        f32x4 acc[2][4] = {};
        for (int kt = 0; kt < 256; kt += 64) {
            async16(xb + (row0 + w * 8 + lr) * 256 + kt + lc, &Asm[w * 512]);
            #pragma unroll
            for (int i = 0; i < 4; ++i) {
                const int ch = i * 8 + w;
                async16(WqT + (long)(ch * 8 + lr) * 256 + kt + lc, &Bsm[ch * 512]);
            }
            __syncthreads();
            #pragma unroll
            for (int ks = 0; ks < 2; ++ks) {
                short8 a[2], bb[4];
                #pragma unroll
                for (int m = 0; m < 2; ++m)
                    a[m] = *(const short8*)&Asm[(wm*32 + m*16 + l15)*64 + ks*32 + lg*8];
                #pragma unroll
                for (int n = 0; n < 4; ++n)
                    bb[n] = *(const short8*)&Bsm[(wn*64 + n*16 + l15)*64 + ks*32 + lg*8];
                #pragma unroll
                for (int m = 0; m < 2; ++m)
                    #pragma unroll
                    for (int n = 0; n < 4; ++n)
                        acc[m][n] = __builtin_amdgcn_mfma_f32_16x16x32_bf16(a[m], bb[n], acc[m][n], 0, 0, 0);
            }
            __syncthreads();
        }
        // Bsm is dead now: pre-issue GEMM2's WmT tile 0 (lands by the next
        // __syncthreads; latency hidden under fmap + attention).
        #pragma unroll
        for (int i = 0; i < 4; ++i) {
            const int ch = i * 8 + w;
            async16(WmT + (long)(ch * 8 + lr) * 256 + lc, &Bsm[ch * 512]);
        }
        // fmap -> QM
        #pragma unroll
        for (int m = 0; m < 2; ++m) {
            #pragma unroll
            for (int n = 0; n < 4; ++n) {
                #pragma unroll
                for (int r = 0; r < 4; ++r) {
                    const int row = wm * 32 + m * 16 + lg * 4 + r;
                    const int col = wn * 64 + n * 16 + l15;
                    float v = acc[m][n][r];
                    v = v > 0.f ? v + 1.f : __expf(v);
                    QM[row * 264 + col] = __float2bfloat16(v);
                }
            }
        }
    }
    __syncthreads();

    {
        const bf16* kvh = KVb + (long)n_b * 12288 + w * 1536;
        short8 b0, b1, bz;
        #pragma unroll
        for (int j = 0; j < 8; ++j) {
            const int drow = (lg * 8 + j) * 48;
            b0[j] = __builtin_bit_cast(short, kvh[drow + l15]);
            b1[j] = __builtin_bit_cast(short, kvh[drow + 16 + l15]);
            bz[j] = __builtin_bit_cast(short, kvh[drow + 32 + l15]);
        }
        f32x4 ra0[4], ra1[4];
        #pragma unroll
        for (int m2 = 0; m2 < 4; ++m2) {
            const short8 a = *(const short8*)&QM[(m2 * 16 + l15) * 264 + w * 32 + lg * 8];
            f32x4 a0 = {}, a1 = {}, az = {};
            a0 = __builtin_amdgcn_mfma_f32_16x16x32_bf16(a, b0, a0, 0, 0, 0);
            a1 = __builtin_amdgcn_mfma_f32_16x16x32_bf16(a, b1, a1, 0, 0, 0);
            az = __builtin_amdgcn_mfma_f32_16x16x32_bf16(a, bz, az, 0, 0, 0);
            #pragma unroll
            for (int r = 0; r < 4; ++r) {
                const float z   = __shfl(az[r], lane & 48);
                const float inv = 8192.f / (z + EPS_ATTN);
                ra0[m2][r] = a0[r] * inv;
                ra1[m2][r] = a1[r] * inv;
            }
        }
        __syncthreads();
        #pragma unroll
        for (int m2 = 0; m2 < 4; ++m2) {
            #pragma unroll
            for (int r = 0; r < 4; ++r) {
                const int row = m2 * 16 + lg * 4 + r;
                QM[row * 264 + w * 32 + l15]      = __float2bfloat16(ra0[m2][r]);
                QM[row * 264 + w * 32 + 16 + l15] = __float2bfloat16(ra1[m2][r]);
            }
        }
    }
    __syncthreads();

    f32x4 acc[2][4] = {};
    for (int kt = 0; kt < 256; kt += 64) {
        if (kt > 0) {                       // tile 0 was pre-issued
            #pragma unroll
            for (int i = 0; i < 4; ++i) {
                const int ch = i * 8 + w;
                async16(WmT + (long)(ch * 8 + lr) * 256 + kt + lc, &Bsm[ch * 512]);
            }
        }
        __syncthreads();
        #pragma unroll
        for (int ks = 0; ks < 2; ++ks) {
            short8 a[2], bb[4];
            #pragma unroll
            for (int m = 0; m < 2; ++m)
                a[m] = *(const short8*)&QM[(wm*32 + m*16 + l15) * 264 + kt + ks*32 + lg*8];
            #pragma unroll
            for (int n = 0; n < 4; ++n)
                bb[n] = *(const short8*)&Bsm[(wn*64 + n*16 + l15)*64 + ks*32 + lg*8];
            #pragma unroll
            for (int m = 0; m < 2; ++m)
                #pragma unroll
                for (int n = 0; n < 4; ++n)
                    acc[m][n] = __builtin_amdgcn_mfma_f32_16x16x32_bf16(a[m], bb[n], acc[m][n], 0, 0, 0);
        }
        __syncthreads();
    }

    #pragma unroll
    for (int m = 0; m < 2; ++m) {
        #pragma unroll
        for (int r = 0; r < 4; ++r) {
            float ls = 0.f, lq = 0.f;
            #pragma unroll
            for (int n = 0; n < 4; ++n) {
                const float v = acc[m][n][r];
                ls += v; lq += v * v;
            }
            #pragma unroll
            for (int o = 1; o < 16; o <<= 1) {
                ls += __shfl_xor(ls, o);
                lq += __shfl_xor(lq, o);
            }
            if (l15 == 0) {
                const int row = wm * 32 + m * 16 + lg * 4 + r;
                lnS[wn][row] = ls;
                lnQ[wn][row] = lq;
            }
        }
    }
    __syncthreads();

    float gv[4], bv[4];
    #pragma unroll
    for (int n = 0; n < 4; ++n) {
        const int col = wn * 64 + n * 16 + l15;
        gv[n] = g[col]; bv[n] = b[col];
    }
    #pragma unroll
    for (int m = 0; m < 2; ++m) {
        #pragma unroll
        for (int r = 0; r < 4; ++r) {
            const int row = wm * 32 + m * 16 + lg * 4 + r;
            const float S  = lnS[0][row] + lnS[1][row] + lnS[2][row] + lnS[3][row];
            const float Qq = lnQ[0][row] + lnQ[1][row] + lnQ[2][row] + lnQ[3][row];
            const float mean = S * (1.f / 256.f);
            const float var  = Qq * (1.f / 256.f) - mean * mean;
            const float rstd = rsqrtf(var + EPS_LN);
            const long grow = row0 + row;
            #pragma unroll
            for (int n = 0; n < 4; ++n) {
                const int col = wn * 64 + n * 16 + l15;
                const float y = (acc[m][n][r] - mean) * rstd * gv[n] + bv[n];
                msgln[grow * 256 + col] = __float2bfloat16(y);
            }
        }
    }
}

// ---------------------------------------------------------------------------
// W1 GEMM, 8-PHASE 256x256 schedule (proven in R11). t = relu([A0|A1] @ W1).
// ---------------------------------------------------------------------------
__global__ __launch_bounds__(512, 2)
void k_gemmW1_8p(const bf16* __restrict__ A0, const bf16* __restrict__ A1,
                 const bf16* __restrict__ BT, bf16* __restrict__ C)
{
    __shared__ __attribute__((aligned(16))) bf16 S[65536];   // 128 KB
    const int t = threadIdx.x, w = t >> 6, lane = t & 63;
    const int wm = w >> 2, wn = w & 3;
    const int lg = lane >> 4, l15 = lane & 15;
    const int orig = blockIdx.y * gridDim.x + blockIdx.x;    // 0..255
    const int swz  = (orig & 7) * 32 + (orig >> 3);          // bijective XCD
    const long row0 = (long)(swz >> 1) * 256;
    const long col0 = (long)(swz & 1) * 256;

    f32x4 acc[8][4] = {};
    short8 av[4], bv0[4], bv1[4];

    auto stageA = [&](int tile, int half) {
        if (tile >= 8) return;
        const bf16* Asrc = (tile < 4) ? A0 : A1;
        const int kbase = (tile & 3) * 64;
        #pragma unroll
        for (int i = 0; i < 2; ++i) {
            const int cbase = i * 512 + w * 64;
            const int c = cbase + lane;
            const int srow = c >> 3;
            const int lcol = 8 * ((c & 7) ^ (srow & 7));
            async16(Asrc + (row0 + half * 128 + srow) * 256 + kbase + lcol,
                    &S[(tile & 1) * 32768 + half * 8192 + cbase * 8]);
        }
    };
    auto stageB = [&](int tile, int half) {
        if (tile >= 8) return;
        const int kbase = tile * 64;
        #pragma unroll
        for (int i = 0; i < 2; ++i) {
            const int cbase = i * 512 + w * 64;
            const int c = cbase + lane;
            const int srow = c >> 3;
            const int lcol = 8 * ((c & 7) ^ (srow & 7));
            async16(BT + (col0 + half * 128 + srow) * 512 + kbase + lcol,
                    &S[(tile & 1) * 32768 + 16384 + half * 8192 + cbase * 8]);
        }
    };

#define RD_A(BUF, MH, KS) do { _Pragma("unroll")                               \
    for (int m_ = 0; m_ < 4; ++m_) {                                           \
        const int row_ = wm * 128 + (MH) * 64 + m_ * 16 + l15;                 \
        av[m_] = *(const short8*)&S[(BUF) * 32768 + row_ * 64 +                \
                 (((KS) * 32 + lg * 8) ^ ((row_ & 7) << 3))]; } } while (0)

#define RD_B(BUF, KS, BV) do { _Pragma("unroll")                               \
    for (int n_ = 0; n_ < 4; ++n_) {                                           \
        const int row_ = wn * 64 + n_ * 16 + l15;                              \
        (BV)[n_] = *(const short8*)&S[(BUF) * 32768 + 16384 + row_ * 64 +      \
                 (((KS) * 32 + lg * 8) ^ ((row_ & 7) << 3))]; } } while (0)

#define DO_MFMA(MH, BV) do { __builtin_amdgcn_s_setprio(1); _Pragma("unroll")  \
    for (int m_ = 0; m_ < 4; ++m_) { _Pragma("unroll")                         \
        for (int n_ = 0; n_ < 4; ++n_)                                         \
            acc[(MH) * 4 + m_][n_] = __builtin_amdgcn_mfma_f32_16x16x32_bf16(  \
                av[m_], (BV)[n_], acc[(MH) * 4 + m_][n_], 0, 0, 0); }          \
    __builtin_amdgcn_s_setprio(0); } while (0)

#define BAR() __builtin_amdgcn_s_barrier()

    stageB(0, 0); stageB(0, 1); stageA(0, 0); stageA(0, 1);
    stageB(1, 0); stageB(1, 1);
    asm volatile("s_waitcnt vmcnt(4)" ::: "memory");
    BAR();

    for (int it = 0; it < 4; ++it) {
        const int T1 = 2 * it + 1;
        RD_B(0, 0, bv0); RD_A(0, 0, 0); stageA(T1, 0);
        BAR(); DO_MFMA(0, bv0); BAR();
        RD_B(0, 1, bv1); RD_A(0, 0, 1); stageA(T1, 1);
        BAR(); DO_MFMA(0, bv1); BAR();
        RD_A(0, 1, 0); stageB(T1 + 1, 0);
        BAR(); DO_MFMA(1, bv0); BAR();
        RD_A(0, 1, 1); stageB(T1 + 1, 1);
        BAR(); DO_MFMA(1, bv1);
        if (it == 3) asm volatile("s_waitcnt vmcnt(0)" ::: "memory");
        else         asm volatile("s_waitcnt vmcnt(4)" ::: "memory");
        BAR();
        RD_B(1, 0, bv0); RD_A(1, 0, 0); stageA(T1 + 1, 0);
        BAR(); DO_MFMA(0, bv0); BAR();
        RD_B(1, 1, bv1); RD_A(1, 0, 1); stageA(T1 + 1, 1);
        BAR(); DO_MFMA(0, bv1); BAR();
        RD_A(1, 1, 0); stageB(T1 + 2, 0);
        BAR(); DO_MFMA(1, bv0); BAR();
        RD_A(1, 1, 1); stageB(T1 + 2, 1);
        BAR(); DO_MFMA(1, bv1);
        if (it < 3) asm volatile("s_waitcnt vmcnt(4)" ::: "memory");
        BAR();
    }

    #pragma unroll
    for (int mi = 0; mi < 8; ++mi) {
        #pragma unroll
        for (int n = 0; n < 4; ++n) {
            #pragma unroll
            for (int r = 0; r < 4; ++r) {
                const long row = row0 + wm * 128 + mi * 16 + lg * 4 + r;
                const long col = col0 + wn * 64 + n * 16 + l15;
                const float v = acc[mi][n][r];
                C[row * 512 + col] = __float2bfloat16(v > 0.f ? v : 0.f);
            }
        }
    }
#undef RD_A
#undef RD_B
#undef DO_MFMA
#undef BAR
}

// ---------------------------------------------------------------------------
// W2 GEMM + LN2 + residual, 8-PHASE 256x256 schedule (at memory floor).
// ---------------------------------------------------------------------------
__global__ __launch_bounds__(512, 2)
void k_ln2_8p(const bf16* __restrict__ A, const bf16* __restrict__ BT,
              const float* __restrict__ g, const float* __restrict__ b,
              const float* __restrict__ xres, float* __restrict__ out)
{
    __shared__ __attribute__((aligned(16))) bf16 S[65536];   // 128 KB
    const int t = threadIdx.x, w = t >> 6, lane = t & 63;
    const int wm = w >> 2, wn = w & 3;
    const int lg = lane >> 4, l15 = lane & 15;
    const int orig = blockIdx.x;                             // 0..127
    const int swz  = (orig & 7) * 16 + (orig >> 3);          // bijective XCD
    const long row0 = (long)swz * 256;

    f32x4 acc[8][4] = {};
    short8 av[4], bv0[4], bv1[4];

    auto stageA = [&](int tile, int half) {
        if (tile >= 8) return;
        const int kbase = tile * 64;
        #pragma unroll
        for (int i = 0; i < 2; ++i) {
            const int cbase = i * 512 + w * 64;
            const int c = cbase + lane;
            const int srow = c >> 3;
            const int lcol = 8 * ((c & 7) ^ (srow & 7));
            async16(A + (row0 + half * 128 + srow) * 512 + kbase + lcol,
                    &S[(tile & 1) * 32768 + half * 8192 + cbase * 8]);
        }
    };
    auto stageB = [&](int tile, int half) {
        if (tile >= 8) return;
        const int kbase = tile * 64;
        #pragma unroll
        for (int i = 0; i < 2; ++i) {
            const int cbase = i * 512 + w * 64;
            const int c = cbase + lane;
            const int srow = c >> 3;
            const int lcol = 8 * ((c & 7) ^ (srow & 7));
            async16(BT + (long)(half * 128 + srow) * 512 + kbase + lcol,
                    &S[(tile & 1) * 32768 + 16384 + half * 8192 + cbase * 8]);
        }
    };

#define RD_A(BUF, MH, KS) do { _Pragma("unroll")                               \
    for (int m_ = 0; m_ < 4; ++m_) {                                           \
        const int row_ = wm * 128 + (MH) * 64 + m_ * 16 + l15;                 \
        av[m_] = *(const short8*)&S[(BUF) * 32768 + row_ * 64 +                \
                 (((KS) * 32 + lg * 8) ^ ((row_ & 7) << 3))]; } } while (0)

#define RD_B(BUF, KS, BV) do { _Pragma("unroll")                               \
    for (int n_ = 0; n_ < 4; ++n_) {                                           \
        const int row_ = wn * 64 + n_ * 16 + l15;                              \
        (BV)[n_] = *(const short8*)&S[(BUF) * 32768 + 16384 + row_ * 64 +      \
                 (((KS) * 32 + lg * 8) ^ ((row_ & 7) << 3))]; } } while (0)

#define DO_MFMA(MH, BV) do { __builtin_amdgcn_s_setprio(1); _Pragma("unroll")  \
    for (int m_ = 0; m_ < 4; ++m_) { _Pragma("unroll")                         \
        for (int n_ = 0; n_ < 4; ++n_)                                         \
            acc[(MH) * 4 + m_][n_] = __builtin_amdgcn_mfma_f32_16x16x32_bf16(  \
                av[m_], (BV)[n_], acc[(MH) * 4 + m_][n_], 0, 0, 0); }          \
    __builtin_amdgcn_s_setprio(0); } while (0)

#define BAR() __builtin_amdgcn_s_barrier()

    stageB(0, 0); stageB(0, 1); stageA(0, 0); stageA(0, 1);
    stageB(1, 0); stageB(1, 1);
    asm volatile("s_waitcnt vmcnt(4)" ::: "memory");
    BAR();

    for (int it = 0; it < 4; ++it) {
        const int T1 = 2 * it + 1;
        RD_B(0, 0, bv0); RD_A(0, 0, 0); stageA(T1, 0);
        BAR(); DO_MFMA(0, bv0); BAR();
        RD_B(0, 1, bv1); RD_A(0, 0, 1); stageA(T1, 1);
        BAR(); DO_MFMA(0, bv1); BAR();
        RD_A(0, 1, 0); stageB(T1 + 1, 0);
        BAR(); DO_MFMA(1, bv0); BAR();
        RD_A(0, 1, 1); stageB(T1 + 1, 1);
        BAR(); DO_MFMA(1, bv1);
        if (it == 3) asm volatile("s_waitcnt vmcnt(0)" ::: "memory");
        else         asm volatile("s_waitcnt vmcnt(4)" ::: "memory");
        BAR();
        RD_B(1, 0, bv0); RD_A(1, 0, 0); stageA(T1 + 1, 0);
        BAR(); DO_MFMA(0, bv0); BAR();
        RD_B(1, 1, bv1); RD_A(1, 0, 1); stageA(T1 + 1, 1);
        BAR(); DO_MFMA(0, bv1); BAR();
        RD_A(1, 1, 0); stageB(T1 + 2, 0);
        BAR(); DO_MFMA(1, bv0); BAR();
        RD_A(1, 1, 1); stageB(T1 + 2, 1);
        BAR(); DO_MFMA(1, bv1);
        if (it < 3) asm volatile("s_waitcnt vmcnt(4)" ::: "memory");
        BAR();
    }

    __syncthreads();
    float* lnS = (float*)S;
    float* lnQ = (float*)((char*)S + 4096);

    #pragma unroll
    for (int mi = 0; mi < 8; ++mi) {
        #pragma unroll
        for (int r = 0; r < 4; ++r) {
            float ls = 0.f, lq = 0.f;
            #pragma unroll
            for (int n = 0; n < 4; ++n) {
                const float v = acc[mi][n][r];
                ls += v; lq += v * v;
            }
            #pragma unroll
            for (int o = 1; o < 16; o <<= 1) {
                ls += __shfl_xor(ls, o);
                lq += __shfl_xor(lq, o);
            }
            if (l15 == 0) {
                const int row = wm * 128 + mi * 16 + lg * 4 + r;
                lnS[wn * 256 + row] = ls;
                lnQ[wn * 256 + row] = lq;
            }
        }
    }
    __syncthreads();

    float gv[4], bv[4];
    #pragma unroll
    for (int n = 0; n < 4; ++n) {
        const int col = wn * 64 + n * 16 + l15;
        gv[n] = g[col]; bv[n] = b[col];
    }
    #pragma unroll
    for (int mi = 0; mi < 8; ++mi) {
        #pragma unroll
        for (int r = 0; r < 4; ++r) {
            const int row = wm * 128 + mi * 16 + lg * 4 + r;
            const float Sm = lnS[row] + lnS[256 + row] + lnS[512 + row] + lnS[768 + row];
            const float Qq = lnQ[row] + lnQ[256 + row] + lnQ[512 + row] + lnQ[768 + row];
            const float mean = Sm * (1.f / 256.f);
            const float var  = Qq * (1.f / 256.f) - mean * mean;
            const float rstd = rsqrtf(var + EPS_LN);
            const long grow = row0 + row;
            #pragma unroll
            for (int n = 0; n < 4; ++n) {
                const int col = wn * 64 + n * 16 + l15;
                const float y = (acc[mi][n][r] - mean) * rstd * gv[n] + bv[n];
                out[grow * 256 + col] = xres[grow * 256 + col] + y;
            }
        }
    }
#undef RD_A
#undef RD_B
#undef DO_MFMA
#undef BAR
}

// ---------------------------------------------------------------------------
extern "C" void kernel_launch(void* const* d_in, const int* in_sizes, int n_in,
                              void* d_out, int out_size, void* d_ws, size_t ws_size,
                              hipStream_t stream)
{
    const float* x      = (const float*)d_in[0];
    const float* source = (const float*)d_in[1];
    const float* Wq     = (const float*)d_in[2];
    const float* Wk     = (const float*)d_in[3];
    const float* Wv     = (const float*)d_in[4];
    const float* Wm     = (const float*)d_in[5];
    const float* W1     = (const float*)d_in[6];
    const float* W2     = (const float*)d_in[7];
    const float* g1     = (const float*)d_in[8];
    const float* b1     = (const float*)d_in[9];
    const float* g2     = (const float*)d_in[10];
    const float* b2     = (const float*)d_in[11];
    float* out = (float*)d_out;

    const size_t U = 32768ull * 256ull;
    char* w = (char*)d_ws;

    bf16* x_bf  = (bf16*)(w + 0 * U * 2);
    bf16* s_bf  = (bf16*)(w + 1 * U * 2);
    bf16* msgln = (bf16*)(w + 2 * U * 2);
    bf16* t_bf  = (bf16*)(w + 3 * U * 2);   // slots 3-4 ([32768,512])

    char* wx = w + 7 * U * 2;
    bf16* WqT = (bf16*)wx; wx += 65536 * 2;
    bf16* WkT = (bf16*)wx; wx += 65536 * 2;   // contiguous with WvT
    bf16* WvT = (bf16*)wx; wx += 65536 * 2;
    bf16* WmT = (bf16*)wx; wx += 65536 * 2;
    bf16* W1T = (bf16*)wx; wx += 262144 * 2;
    bf16* W2T = (bf16*)wx; wx += 131072 * 2;
    bf16* partKV = (bf16*)wx; wx += 2097152 * 2;   // 256 cid x 8192
    float* partKs = (float*)wx; wx += 65536 * 4;   // 256 cid x 256
    bf16* part2  = (bf16*)wx; wx += 262144 * 2;    // 8 x 4 x 8192
    float* part2Ks = (float*)wx; wx += 8192 * 4;   // 8 x 4 x 256
    bf16* KVb    = (bf16*)wx; wx += 49152 * 2;     // [n][h][32][48]

    const dim3 blk(256);

    // 1) prep
    k_prep<<<8352, blk, 0, stream>>>(x, source, x_bf, s_bf,
                                     Wq, Wk, Wv, Wm, W1, W2,
                                     WqT, WkT, WvT, WmT, W1T, W2T);

    // 2) fused K/V projection + partial KV/Ksum
    k_kvproj<<<dim3(256, 2), dim3(512), 0, stream>>>(s_bf, WkT, partKV, partKs,
                                                     1.f / 8192.f);

    // 3) 2-stage reduce -> KVaug (R12 config)
    k_kvred1<<<256, blk, 0, stream>>>(partKV, partKs, part2, part2Ks);
    k_kvred2<<<32, blk, 0, stream>>>(part2, part2Ks, KVb);

    // 4) MEGA (R12 2-phase + WmT tile-0 prefetch): Q-proj+attn+merge+LN1
    k_qaml<<<512, dim3(512), 0, stream>>>(x_bf, WqT, WmT, KVb, g1, b1, msgln);

    // 5) MLP: 8-phase W1; 8-phase W2+LN2+residual
    k_gemmW1_8p<<<dim3(128, 2), dim3(512), 0, stream>>>(x_bf, msgln, W1T, t_bf);
    k_ln2_8p<<<128, dim3(512), 0, stream>>>(t_bf, W2T, g2, b2, x, out);
}

// Round 15
// 130.728 us; speedup vs baseline: 1.0459x; 1.0015x over previous
//
#include <hip/hip_runtime.h>
#include <hip/hip_bf16.h>
#include <stdint.h>

typedef __hip_bfloat16 bf16;
typedef __attribute__((ext_vector_type(8))) short short8;
typedef __attribute__((ext_vector_type(4))) short bf16x4;
typedef __attribute__((ext_vector_type(4))) float f32x4;

#define EPS_ATTN 1e-6f
#define EPS_LN   1e-5f

__device__ __forceinline__ float b2f(short s) {
    return __builtin_bit_cast(float, (unsigned)((unsigned short)s) << 16);
}
__device__ __forceinline__ short f2b(float f) {
    return __builtin_bit_cast(short, __float2bfloat16(f));
}

// ---------------------------------------------------------------------------
// async global->LDS, 16B per lane. LDS dest = wave-uniform base + lane*16.
// ---------------------------------------------------------------------------
__device__ __forceinline__ void async16(const void* g, void* l) {
    __builtin_amdgcn_global_load_lds(
        (const __attribute__((address_space(1))) void*)g,
        (__attribute__((address_space(3))) void*)l,
        16, 0, 0);
}

// ---------------------------------------------------------------------------
// Prep: fp32->bf16 converts (x, source) + all 6 weight transposes, ONE launch.
// ---------------------------------------------------------------------------
__global__ __launch_bounds__(256)
void k_prep(const float* __restrict__ x, const float* __restrict__ src,
            bf16* __restrict__ x_bf, bf16* __restrict__ s_bf,
            const float* __restrict__ Wq, const float* __restrict__ Wk,
            const float* __restrict__ Wv, const float* __restrict__ Wm,
            const float* __restrict__ W1, const float* __restrict__ W2,
            bf16* __restrict__ WqT, bf16* __restrict__ WkT,
            bf16* __restrict__ WvT, bf16* __restrict__ WmT,
            bf16* __restrict__ W1T, bf16* __restrict__ W2T)
{
    __shared__ float tile[64][65];
    const int blk = blockIdx.x;
    if (blk < 8192) {
        const float* in = (blk < 4096) ? x : src;
        bf16* out       = (blk < 4096) ? x_bf : s_bf;
        const long id = (long)(blk & 4095) * 256 + threadIdx.x;
        const float4 a = ((const float4*)in)[id * 2];
        const float4 b = ((const float4*)in)[id * 2 + 1];
        short8 o;
        o[0] = f2b(a.x); o[1] = f2b(a.y); o[2] = f2b(a.z); o[3] = f2b(a.w);
        o[4] = f2b(b.x); o[5] = f2b(b.y); o[6] = f2b(b.z); o[7] = f2b(b.w);
        ((short8*)out)[id] = o;
        return;
    }
    const int b = blk - 8192;
    const float* W; bf16* WT; int K, N, local;
    if      (b < 16)  { W = Wq; WT = WqT; K = 256; N = 256; local = b; }
    else if (b < 32)  { W = Wk; WT = WkT; K = 256; N = 256; local = b - 16; }
    else if (b < 48)  { W = Wv; WT = WvT; K = 256; N = 256; local = b - 32; }
    else if (b < 64)  { W = Wm; WT = WmT; K = 256; N = 256; local = b - 48; }
    else if (b < 128) { W = W1; WT = W1T; K = 512; N = 512; local = b - 64; }
    else              { W = W2; WT = W2T; K = 512; N = 256; local = b - 128; }
    const int tk = K / 64;
    const int k0 = (local % tk) * 64, n0 = (local / tk) * 64;
    const int ty = threadIdx.x >> 4, tx = threadIdx.x & 15;
    #pragma unroll
    for (int i = 0; i < 4; ++i) {
        const int k = ty + i * 16;
        const float4 v = *(const float4*)&W[(long)(k0 + k) * N + n0 + tx * 4];
        tile[k][tx * 4 + 0] = v.x; tile[k][tx * 4 + 1] = v.y;
        tile[k][tx * 4 + 2] = v.z; tile[k][tx * 4 + 3] = v.w;
    }
    __syncthreads();
    #pragma unroll
    for (int i = 0; i < 4; ++i) {
        const int n = ty + i * 16;
        bf16x4 o;
        #pragma unroll
        for (int j = 0; j < 4; ++j) o[j] = f2b(tile[tx * 4 + j][n]);
        *(bf16x4*)&WT[(long)(n0 + n) * K + k0 + tx * 4] = o;
    }
}

// ---------------------------------------------------------------------------
// FUSED K/V projection + feature-map + partial-KV/Ksum (proven in R9).
// ---------------------------------------------------------------------------
__global__ __launch_bounds__(512)
void k_kvproj(const bf16* __restrict__ A, const bf16* __restrict__ BT,
              bf16* __restrict__ partKV, float* __restrict__ partKs,
              float escale)
{
    __shared__ __attribute__((aligned(16))) bf16 S[32768];   // 64 KB union
    bf16* Asm = S;
    bf16* Bsm = S + 8192;
    bf16* KT  = S;
    bf16* VT  = S + 16384;

    const int t = threadIdx.x, w = t >> 6, lane = t & 63;
    const int wm = w >> 2, wn = w & 3;
    const int flat = blockIdx.y * gridDim.x + blockIdx.x;   // 0..511
    const int swz  = (flat & 7) * 64 + (flat >> 3);         // bijective, XCD
    const int cid  = swz >> 1;
    const int hh   = swz & 1;
    const long row0 = (long)cid * 128;
    const int lr = lane >> 3, lc = (lane & 7) * 8;
    const int lg = lane >> 4, l15 = lane & 15;

    f32x4 acc[4][4] = {};

    for (int kt = 0; kt < 256; kt += 64) {
        #pragma unroll
        for (int i = 0; i < 2; ++i) {
            const int g = w * 2 + i;
            async16(A + (row0 + g * 8 + lr) * 256 + kt + lc, &Asm[g * 512]);
        }
        #pragma unroll
        for (int i = 0; i < 4; ++i) {
            const int g = w * 4 + i;
            const long brow = (g < 16)
                ? (long)(hh * 128 + g * 8 + lr)
                : (long)(256 + hh * 128 + (g - 16) * 8 + lr);
            async16(BT + brow * 256 + kt + lc, &Bsm[g * 512]);
        }
        __syncthreads();
        #pragma unroll
        for (int ks = 0; ks < 2; ++ks) {
            short8 a[4], b[4];
            #pragma unroll
            for (int m = 0; m < 4; ++m)
                a[m] = *(const short8*)&Asm[(wm*64 + m*16 + l15)*64 + ks*32 + lg*8];
            #pragma unroll
            for (int n = 0; n < 4; ++n)
                b[n] = *(const short8*)&Bsm[(wn*64 + n*16 + l15)*64 + ks*32 + lg*8];
            #pragma unroll
            for (int m = 0; m < 4; ++m)
                #pragma unroll
                for (int n = 0; n < 4; ++n)
                    acc[m][n] = __builtin_amdgcn_mfma_f32_16x16x32_bf16(a[m], b[n], acc[m][n], 0, 0, 0);
        }
        __syncthreads();
    }

    const bool isK = wn < 2;
    bf16* tile = isK ? KT : VT;
    #pragma unroll
    for (int m = 0; m < 4; ++m) {
        #pragma unroll
        for (int n = 0; n < 4; ++n) {
            #pragma unroll
            for (int r = 0; r < 4; ++r) {
                const int row = wm * 64 + m * 16 + lg * 4 + r;
                const int col = (wn & 1) * 64 + n * 16 + l15;
                float v = acc[m][n][r];
                if (isK) v = v > 0.f ? v + 1.f : __expf(v);
                else     v *= escale;
                tile[row * 128 + col] = __float2bfloat16(v);
            }
        }
    }
    __syncthreads();

    const int h_l = t >> 7;
    const int d   = (t & 127) >> 2;
    const int vg  = t & 3;
    float a2[8] = {};
    float ks = 0.f;
    #pragma unroll 4
    for (int row = 0; row < 128; ++row) {
        const float kd = __bfloat162float(KT[row * 128 + h_l * 32 + d]);
        ks += kd;
        const short8 vv = *(const short8*)&VT[row * 128 + h_l * 32 + vg * 8];
        #pragma unroll
        for (int u = 0; u < 8; ++u) a2[u] += kd * b2f(vv[u]);
    }
    short8 o;
    #pragma unroll
    for (int u = 0; u < 8; ++u) o[u] = f2b(a2[u]);
    *(short8*)&partKV[(long)cid * 8192 + (hh * 4 + h_l) * 1024 + d * 32 + vg * 8] = o;
    if (vg == 0) partKs[cid * 256 + (hh * 4 + h_l) * 32 + d] = ks;
}

// ---------------------------------------------------------------------------
// MERGED KV reduce, one launch: 256 cid partials -> KVaug bf16 [n][h][32][48].
// Grid 32 = (n<<3)|h, 1024 threads: quarter q = t>>8 sums 16 cids for slot
// s = t&255 (d = s>>3, vg = s&7); 4-way LDS tree reduce. All-fp32 accum.
// ---------------------------------------------------------------------------
__global__ __launch_bounds__(1024)
void k_kvredM(const bf16* __restrict__ partKV, const float* __restrict__ partKs,
              bf16* __restrict__ KVb)
{
    __shared__ float red[4][256][4];   // 16 KB
    __shared__ float redK[4][32];
    const int bk = blockIdx.x;
    const int n = bk >> 3, h = bk & 7;
    const int t = threadIdx.x;
    const int q = t >> 8;              // cid quarter 0..3
    const int s = t & 255;             // slot
    const int d = s >> 3, vg = s & 7;

    float sum[4] = {};
    #pragma unroll
    for (int i = 0; i < 16; ++i) {
        const int cid = n * 64 + q * 16 + i;
        const bf16x4 p = *(const bf16x4*)&partKV[(long)cid * 8192 + h * 1024 + d * 32 + vg * 4];
        #pragma unroll
        for (int j = 0; j < 4; ++j) sum[j] += b2f(p[j]);
    }
    #pragma unroll
    for (int j = 0; j < 4; ++j) red[q][s][j] = sum[j];
    if (vg == 0) {
        float ks = 0.f;
        #pragma unroll
        for (int i = 0; i < 16; ++i)
            ks += partKs[(n * 64 + q * 16 + i) * 256 + h * 32 + d];
        redK[q][d] = ks;
    }
    __syncthreads();

    if (q == 0) {
        bf16* dst = KVb + ((long)n * 8 + h) * 1536 + d * 48;
        bf16x4 o;
        #pragma unroll
        for (int j = 0; j < 4; ++j) {
            const float tot = red[0][s][j] + red[1][s][j] + red[2][s][j] + red[3][s][j];
            o[j] = f2b(tot);
        }
        *(bf16x4*)&dst[vg * 4] = o;
        if (vg == 0) {
            const float kt = redK[0][d] + redK[1][d] + redK[2][d] + redK[3][d];
            short8 z0 = {};
            z0[0] = f2b(kt);
            *(short8*)&dst[32] = z0;           // cols 32..39 (32 = Ksum)
            short8 zz = {};
            *(short8*)&dst[40] = zz;           // cols 40..47
        }
    }
}

// ---------------------------------------------------------------------------
// MEGA: Q-proj + feature-map + attention + merge-GEMM + LN1 (R12 2-phase,
// 2 blocks/CU, + WmT tile-0 prefetch from R14).
// ---------------------------------------------------------------------------
__global__ __launch_bounds__(512)
void k_qaml(const bf16* __restrict__ xb, const bf16* __restrict__ WqT,
            const bf16* __restrict__ WmT, const bf16* __restrict__ KVb,
            const float* __restrict__ g, const float* __restrict__ b,
            bf16* __restrict__ msgln)
{
    __shared__ __attribute__((aligned(16))) bf16 Asm[64 * 64];
    __shared__ __attribute__((aligned(16))) bf16 Bsm[256 * 64];
    __shared__ __attribute__((aligned(16))) bf16 QM[64 * 264];
    __shared__ float lnS[4][64];
    __shared__ float lnQ[4][64];
    const int t = threadIdx.x, w = t >> 6, lane = t & 63;
    const int wm = w >> 2, wn = w & 3;
    const long row0 = (long)blockIdx.x * 64;
    const int n_b = (int)(row0 >> 13);
    const int lr = lane >> 3, lc = (lane & 7) * 8;
    const int lg = lane >> 4, l15 = lane & 15;

    {
        f32x4 acc[2][4] = {};
        for (int kt = 0; kt < 256; kt += 64) {
            async16(xb + (row0 + w * 8 + lr) * 256 + kt + lc, &Asm[w * 512]);
            #pragma unroll
            for (int i = 0; i < 4; ++i) {
                const int ch = i * 8 + w;
                async16(WqT + (long)(ch * 8 + lr) * 256 + kt + lc, &Bsm[ch * 512]);
            }
            __syncthreads();
            #pragma unroll
            for (int ks = 0; ks < 2; ++ks) {
                short8 a[2], bb[4];
                #pragma unroll
                for (int m = 0; m < 2; ++m)
                    a[m] = *(const short8*)&Asm[(wm*32 + m*16 + l15)*64 + ks*32 + lg*8];
                #pragma unroll
                for (int n = 0; n < 4; ++n)
                    bb[n] = *(const short8*)&Bsm[(wn*64 + n*16 + l15)*64 + ks*32 + lg*8];
                #pragma unroll
                for (int m = 0; m < 2; ++m)
                    #pragma unroll
                    for (int n = 0; n < 4; ++n)
                        acc[m][n] = __builtin_amdgcn_mfma_f32_16x16x32_bf16(a[m], bb[n], acc[m][n], 0, 0, 0);
            }
            __syncthreads();
        }
        // Bsm dead: pre-issue GEMM2's WmT tile 0 (latency hidden under
        // fmap + attention; lands by the next __syncthreads).
        #pragma unroll
        for (int i = 0; i < 4; ++i) {
            const int ch = i * 8 + w;
            async16(WmT + (long)(ch * 8 + lr) * 256 + lc, &Bsm[ch * 512]);
        }
        // fmap -> QM
        #pragma unroll
        for (int m = 0; m < 2; ++m) {
            #pragma unroll
            for (int n = 0; n < 4; ++n) {
                #pragma unroll
                for (int r = 0; r < 4; ++r) {
                    const int row = wm * 32 + m * 16 + lg * 4 + r;
                    const int col = wn * 64 + n * 16 + l15;
                    float v = acc[m][n][r];
                    v = v > 0.f ? v + 1.f : __expf(v);
                    QM[row * 264 + col] = __float2bfloat16(v);
                }
            }
        }
    }
    __syncthreads();

    {
        const bf16* kvh = KVb + (long)n_b * 12288 + w * 1536;
        short8 b0, b1, bz;
        #pragma unroll
        for (int j = 0; j < 8; ++j) {
            const int drow = (lg * 8 + j) * 48;
            b0[j] = __builtin_bit_cast(short, kvh[drow + l15]);
            b1[j] = __builtin_bit_cast(short, kvh[drow + 16 + l15]);
            bz[j] = __builtin_bit_cast(short, kvh[drow + 32 + l15]);
        }
        f32x4 ra0[4], ra1[4];
        #pragma unroll
        for (int m2 = 0; m2 < 4; ++m2) {
            const short8 a = *(const short8*)&QM[(m2 * 16 + l15) * 264 + w * 32 + lg * 8];
            f32x4 a0 = {}, a1 = {}, az = {};
            a0 = __builtin_amdgcn_mfma_f32_16x16x32_bf16(a, b0, a0, 0, 0, 0);
            a1 = __builtin_amdgcn_mfma_f32_16x16x32_bf16(a, b1, a1, 0, 0, 0);
            az = __builtin_amdgcn_mfma_f32_16x16x32_bf16(a, bz, az, 0, 0, 0);
            #pragma unroll
            for (int r = 0; r < 4; ++r) {
                const float z   = __shfl(az[r], lane & 48);
                const float inv = 8192.f / (z + EPS_ATTN);
                ra0[m2][r] = a0[r] * inv;
                ra1[m2][r] = a1[r] * inv;
            }
        }
        __syncthreads();
        #pragma unroll
        for (int m2 = 0; m2 < 4; ++m2) {
            #pragma unroll
            for (int r = 0; r < 4; ++r) {
                const int row = m2 * 16 + lg * 4 + r;
                QM[row * 264 + w * 32 + l15]      = __float2bfloat16(ra0[m2][r]);
                QM[row * 264 + w * 32 + 16 + l15] = __float2bfloat16(ra1[m2][r]);
            }
        }
    }
    __syncthreads();

    f32x4 acc[2][4] = {};
    for (int kt = 0; kt < 256; kt += 64) {
        if (kt > 0) {
            #pragma unroll
            for (int i = 0; i < 4; ++i) {
                const int ch = i * 8 + w;
                async16(WmT + (long)(ch * 8 + lr) * 256 + kt + lc, &Bsm[ch * 512]);
            }
        }
        __syncthreads();
        #pragma unroll
        for (int ks = 0; ks < 2; ++ks) {
            short8 a[2], bb[4];
            #pragma unroll
            for (int m = 0; m < 2; ++m)
                a[m] = *(const short8*)&QM[(wm*32 + m*16 + l15) * 264 + kt + ks*32 + lg*8];
            #pragma unroll
            for (int n = 0; n < 4; ++n)
                bb[n] = *(const short8*)&Bsm[(wn*64 + n*16 + l15)*64 + ks*32 + lg*8];
            #pragma unroll
            for (int m = 0; m < 2; ++m)
                #pragma unroll
                for (int n = 0; n < 4; ++n)
                    acc[m][n] = __builtin_amdgcn_mfma_f32_16x16x32_bf16(a[m], bb[n], acc[m][n], 0, 0, 0);
        }
        __syncthreads();
    }

    #pragma unroll
    for (int m = 0; m < 2; ++m) {
        #pragma unroll
        for (int r = 0; r < 4; ++r) {
            float ls = 0.f, lq = 0.f;
            #pragma unroll
            for (int n = 0; n < 4; ++n) {
                const float v = acc[m][n][r];
                ls += v; lq += v * v;
            }
            #pragma unroll
            for (int o = 1; o < 16; o <<= 1) {
                ls += __shfl_xor(ls, o);
                lq += __shfl_xor(lq, o);
            }
            if (l15 == 0) {
                const int row = wm * 32 + m * 16 + lg * 4 + r;
                lnS[wn][row] = ls;
                lnQ[wn][row] = lq;
            }
        }
    }
    __syncthreads();

    float gv[4], bv[4];
    #pragma unroll
    for (int n = 0; n < 4; ++n) {
        const int col = wn * 64 + n * 16 + l15;
        gv[n] = g[col]; bv[n] = b[col];
    }
    #pragma unroll
    for (int m = 0; m < 2; ++m) {
        #pragma unroll
        for (int r = 0; r < 4; ++r) {
            const int row = wm * 32 + m * 16 + lg * 4 + r;
            const float S  = lnS[0][row] + lnS[1][row] + lnS[2][row] + lnS[3][row];
            const float Qq = lnQ[0][row] + lnQ[1][row] + lnQ[2][row] + lnQ[3][row];
            const float mean = S * (1.f / 256.f);
            const float var  = Qq * (1.f / 256.f) - mean * mean;
            const float rstd = rsqrtf(var + EPS_LN);
            const long grow = row0 + row;
            #pragma unroll
            for (int n = 0; n < 4; ++n) {
                const int col = wn * 64 + n * 16 + l15;
                const float y = (acc[m][n][r] - mean) * rstd * gv[n] + bv[n];
                msgln[grow * 256 + col] = __float2bfloat16(y);
            }
        }
    }
}

// ---------------------------------------------------------------------------
// W1 GEMM, 8-PHASE 256x256 schedule (proven in R11). t = relu([A0|A1] @ W1).
// ---------------------------------------------------------------------------
__global__ __launch_bounds__(512, 2)
void k_gemmW1_8p(const bf16* __restrict__ A0, const bf16* __restrict__ A1,
                 const bf16* __restrict__ BT, bf16* __restrict__ C)
{
    __shared__ __attribute__((aligned(16))) bf16 S[65536];   // 128 KB
    const int t = threadIdx.x, w = t >> 6, lane = t & 63;
    const int wm = w >> 2, wn = w & 3;
    const int lg = lane >> 4, l15 = lane & 15;
    const int orig = blockIdx.y * gridDim.x + blockIdx.x;    // 0..255
    const int swz  = (orig & 7) * 32 + (orig >> 3);          // bijective XCD
    const long row0 = (long)(swz >> 1) * 256;
    const long col0 = (long)(swz & 1) * 256;

    f32x4 acc[8][4] = {};
    short8 av[4], bv0[4], bv1[4];

    auto stageA = [&](int tile, int half) {
        if (tile >= 8) return;
        const bf16* Asrc = (tile < 4) ? A0 : A1;
        const int kbase = (tile & 3) * 64;
        #pragma unroll
        for (int i = 0; i < 2; ++i) {
            const int cbase = i * 512 + w * 64;
            const int c = cbase + lane;
            const int srow = c >> 3;
            const int lcol = 8 * ((c & 7) ^ (srow & 7));
            async16(Asrc + (row0 + half * 128 + srow) * 256 + kbase + lcol,
                    &S[(tile & 1) * 32768 + half * 8192 + cbase * 8]);
        }
    };
    auto stageB = [&](int tile, int half) {
        if (tile >= 8) return;
        const int kbase = tile * 64;
        #pragma unroll
        for (int i = 0; i < 2; ++i) {
            const int cbase = i * 512 + w * 64;
            const int c = cbase + lane;
            const int srow = c >> 3;
            const int lcol = 8 * ((c & 7) ^ (srow & 7));
            async16(BT + (col0 + half * 128 + srow) * 512 + kbase + lcol,
                    &S[(tile & 1) * 32768 + 16384 + half * 8192 + cbase * 8]);
        }
    };

#define RD_A(BUF, MH, KS) do { _Pragma("unroll")                               \
    for (int m_ = 0; m_ < 4; ++m_) {                                           \
        const int row_ = wm * 128 + (MH) * 64 + m_ * 16 + l15;                 \
        av[m_] = *(const short8*)&S[(BUF) * 32768 + row_ * 64 +                \
                 (((KS) * 32 + lg * 8) ^ ((row_ & 7) << 3))]; } } while (0)

#define RD_B(BUF, KS, BV) do { _Pragma("unroll")                               \
    for (int n_ = 0; n_ < 4; ++n_) {                                           \
        const int row_ = wn * 64 + n_ * 16 + l15;                              \
        (BV)[n_] = *(const short8*)&S[(BUF) * 32768 + 16384 + row_ * 64 +      \
                 (((KS) * 32 + lg * 8) ^ ((row_ & 7) << 3))]; } } while (0)

#define DO_MFMA(MH, BV) do { __builtin_amdgcn_s_setprio(1); _Pragma("unroll")  \
    for (int m_ = 0; m_ < 4; ++m_) { _Pragma("unroll")                         \
        for (int n_ = 0; n_ < 4; ++n_)                                         \
            acc[(MH) * 4 + m_][n_] = __builtin_amdgcn_mfma_f32_16x16x32_bf16(  \
                av[m_], (BV)[n_], acc[(MH) * 4 + m_][n_], 0, 0, 0); }          \
    __builtin_amdgcn_s_setprio(0); } while (0)

#define BAR() __builtin_amdgcn_s_barrier()

    stageB(0, 0); stageB(0, 1); stageA(0, 0); stageA(0, 1);
    stageB(1, 0); stageB(1, 1);
    asm volatile("s_waitcnt vmcnt(4)" ::: "memory");
    BAR();

    for (int it = 0; it < 4; ++it) {
        const int T1 = 2 * it + 1;
        RD_B(0, 0, bv0); RD_A(0, 0, 0); stageA(T1, 0);
        BAR(); DO_MFMA(0, bv0); BAR();
        RD_B(0, 1, bv1); RD_A(0, 0, 1); stageA(T1, 1);
        BAR(); DO_MFMA(0, bv1); BAR();
        RD_A(0, 1, 0); stageB(T1 + 1, 0);
        BAR(); DO_MFMA(1, bv0); BAR();
        RD_A(0, 1, 1); stageB(T1 + 1, 1);
        BAR(); DO_MFMA(1, bv1);
        if (it == 3) asm volatile("s_waitcnt vmcnt(0)" ::: "memory");
        else         asm volatile("s_waitcnt vmcnt(4)" ::: "memory");
        BAR();
        RD_B(1, 0, bv0); RD_A(1, 0, 0); stageA(T1 + 1, 0);
        BAR(); DO_MFMA(0, bv0); BAR();
        RD_B(1, 1, bv1); RD_A(1, 0, 1); stageA(T1 + 1, 1);
        BAR(); DO_MFMA(0, bv1); BAR();
        RD_A(1, 1, 0); stageB(T1 + 2, 0);
        BAR(); DO_MFMA(1, bv0); BAR();
        RD_A(1, 1, 1); stageB(T1 + 2, 1);
        BAR(); DO_MFMA(1, bv1);
        if (it < 3) asm volatile("s_waitcnt vmcnt(4)" ::: "memory");
        BAR();
    }

    #pragma unroll
    for (int mi = 0; mi < 8; ++mi) {
        #pragma unroll
        for (int n = 0; n < 4; ++n) {
            #pragma unroll
            for (int r = 0; r < 4; ++r) {
                const long row = row0 + wm * 128 + mi * 16 + lg * 4 + r;
                const long col = col0 + wn * 64 + n * 16 + l15;
                const float v = acc[mi][n][r];
                C[row * 512 + col] = __float2bfloat16(v > 0.f ? v : 0.f);
            }
        }
    }
#undef RD_A
#undef RD_B
#undef DO_MFMA
#undef BAR
}

// ---------------------------------------------------------------------------
// W2 GEMM + LN2 + residual, 8-PHASE 256x256 schedule (at memory floor).
// ---------------------------------------------------------------------------
__global__ __launch_bounds__(512, 2)
void k_ln2_8p(const bf16* __restrict__ A, const bf16* __restrict__ BT,
              const float* __restrict__ g, const float* __restrict__ b,
              const float* __restrict__ xres, float* __restrict__ out)
{
    __shared__ __attribute__((aligned(16))) bf16 S[65536];   // 128 KB
    const int t = threadIdx.x, w = t >> 6, lane = t & 63;
    const int wm = w >> 2, wn = w & 3;
    const int lg = lane >> 4, l15 = lane & 15;
    const int orig = blockIdx.x;                             // 0..127
    const int swz  = (orig & 7) * 16 + (orig >> 3);          // bijective XCD
    const long row0 = (long)swz * 256;

    f32x4 acc[8][4] = {};
    short8 av[4], bv0[4], bv1[4];

    auto stageA = [&](int tile, int half) {
        if (tile >= 8) return;
        const int kbase = tile * 64;
        #pragma unroll
        for (int i = 0; i < 2; ++i) {
            const int cbase = i * 512 + w * 64;
            const int c = cbase + lane;
            const int srow = c >> 3;
            const int lcol = 8 * ((c & 7) ^ (srow & 7));
            async16(A + (row0 + half * 128 + srow) * 512 + kbase + lcol,
                    &S[(tile & 1) * 32768 + half * 8192 + cbase * 8]);
        }
    };
    auto stageB = [&](int tile, int half) {
        if (tile >= 8) return;
        const int kbase = tile * 64;
        #pragma unroll
        for (int i = 0; i < 2; ++i) {
            const int cbase = i * 512 + w * 64;
            const int c = cbase + lane;
            const int srow = c >> 3;
            const int lcol = 8 * ((c & 7) ^ (srow & 7));
            async16(BT + (long)(half * 128 + srow) * 512 + kbase + lcol,
                    &S[(tile & 1) * 32768 + 16384 + half * 8192 + cbase * 8]);
        }
    };

#define RD_A(BUF, MH, KS) do { _Pragma("unroll")                               \
    for (int m_ = 0; m_ < 4; ++m_) {                                           \
        const int row_ = wm * 128 + (MH) * 64 + m_ * 16 + l15;                 \
        av[m_] = *(const short8*)&S[(BUF) * 32768 + row_ * 64 +                \
                 (((KS) * 32 + lg * 8) ^ ((row_ & 7) << 3))]; } } while (0)

#define RD_B(BUF, KS, BV) do { _Pragma("unroll")                               \
    for (int n_ = 0; n_ < 4; ++n_) {                                           \
        const int row_ = wn * 64 + n_ * 16 + l15;                              \
        (BV)[n_] = *(const short8*)&S[(BUF) * 32768 + 16384 + row_ * 64 +      \
                 (((KS) * 32 + lg * 8) ^ ((row_ & 7) << 3))]; } } while (0)

#define DO_MFMA(MH, BV) do { __builtin_amdgcn_s_setprio(1); _Pragma("unroll")  \
    for (int m_ = 0; m_ < 4; ++m_) { _Pragma("unroll")                         \
        for (int n_ = 0; n_ < 4; ++n_)                                         \
            acc[(MH) * 4 + m_][n_] = __builtin_amdgcn_mfma_f32_16x16x32_bf16(  \
                av[m_], (BV)[n_], acc[(MH) * 4 + m_][n_], 0, 0, 0); }          \
    __builtin_amdgcn_s_setprio(0); } while (0)

#define BAR() __builtin_amdgcn_s_barrier()

    stageB(0, 0); stageB(0, 1); stageA(0, 0); stageA(0, 1);
    stageB(1, 0); stageB(1, 1);
    asm volatile("s_waitcnt vmcnt(4)" ::: "memory");
    BAR();

    for (int it = 0; it < 4; ++it) {
        const int T1 = 2 * it + 1;
        RD_B(0, 0, bv0); RD_A(0, 0, 0); stageA(T1, 0);
        BAR(); DO_MFMA(0, bv0); BAR();
        RD_B(0, 1, bv1); RD_A(0, 0, 1); stageA(T1, 1);
        BAR(); DO_MFMA(0, bv1); BAR();
        RD_A(0, 1, 0); stageB(T1 + 1, 0);
        BAR(); DO_MFMA(1, bv0); BAR();
        RD_A(0, 1, 1); stageB(T1 + 1, 1);
        BAR(); DO_MFMA(1, bv1);
        if (it == 3) asm volatile("s_waitcnt vmcnt(0)" ::: "memory");
        else         asm volatile("s_waitcnt vmcnt(4)" ::: "memory");
        BAR();
        RD_B(1, 0, bv0); RD_A(1, 0, 0); stageA(T1 + 1, 0);
        BAR(); DO_MFMA(0, bv0); BAR();
        RD_B(1, 1, bv1); RD_A(1, 0, 1); stageA(T1 + 1, 1);
        BAR(); DO_MFMA(0, bv1); BAR();
        RD_A(1, 1, 0); stageB(T1 + 2, 0);
        BAR(); DO_MFMA(1, bv0); BAR();
        RD_A(1, 1, 1); stageB(T1 + 2, 1);
        BAR(); DO_MFMA(1, bv1);
        if (it < 3) asm volatile("s_waitcnt vmcnt(4)" ::: "memory");
        BAR();
    }

    __syncthreads();
    float* lnS = (float*)S;
    float* lnQ = (float*)((char*)S + 4096);

    #pragma unroll
    for (int mi = 0; mi < 8; ++mi) {
        #pragma unroll
        for (int r = 0; r < 4; ++r) {
            float ls = 0.f, lq = 0.f;
            #pragma unroll
            for (int n = 0; n < 4; ++n) {
                const float v = acc[mi][n][r];
                ls += v; lq += v * v;
            }
            #pragma unroll
            for (int o = 1; o < 16; o <<= 1) {
                ls += __shfl_xor(ls, o);
                lq += __shfl_xor(lq, o);
            }
            if (l15 == 0) {
                const int row = wm * 128 + mi * 16 + lg * 4 + r;
                lnS[wn * 256 + row] = ls;
                lnQ[wn * 256 + row] = lq;
            }
        }
    }
    __syncthreads();

    float gv[4], bv[4];
    #pragma unroll
    for (int n = 0; n < 4; ++n) {
        const int col = wn * 64 + n * 16 + l15;
        gv[n] = g[col]; bv[n] = b[col];
    }
    #pragma unroll
    for (int mi = 0; mi < 8; ++mi) {
        #pragma unroll
        for (int r = 0; r < 4; ++r) {
            const int row = wm * 128 + mi * 16 + lg * 4 + r;
            const float Sm = lnS[row] + lnS[256 + row] + lnS[512 + row] + lnS[768 + row];
            const float Qq = lnQ[row] + lnQ[256 + row] + lnQ[512 + row] + lnQ[768 + row];
            const float mean = Sm * (1.f / 256.f);
            const float var  = Qq * (1.f / 256.f) - mean * mean;
            const float rstd = rsqrtf(var + EPS_LN);
            const long grow = row0 + row;
            #pragma unroll
            for (int n = 0; n < 4; ++n) {
                const int col = wn * 64 + n * 16 + l15;
                const float y = (acc[mi][n][r] - mean) * rstd * gv[n] + bv[n];
                out[grow * 256 + col] = xres[grow * 256 + col] + y;
            }
        }
    }
#undef RD_A
#undef RD_B
#undef DO_MFMA
#undef BAR
}

// ---------------------------------------------------------------------------
extern "C" void kernel_launch(void* const* d_in, const int* in_sizes, int n_in,
                              void* d_out, int out_size, void* d_ws, size_t ws_size,
                              hipStream_t stream)
{
    const float* x      = (const float*)d_in[0];
    const float* source = (const float*)d_in[1];
    const float* Wq     = (const float*)d_in[2];
    const float* Wk     = (const float*)d_in[3];
    const float* Wv     = (const float*)d_in[4];
    const float* Wm     = (const float*)d_in[5];
    const float* W1     = (const float*)d_in[6];
    const float* W2     = (const float*)d_in[7];
    const float* g1     = (const float*)d_in[8];
    const float* b1     = (const float*)d_in[9];
    const float* g2     = (const float*)d_in[10];
    const float* b2     = (const float*)d_in[11];
    float* out = (float*)d_out;

    const size_t U = 32768ull * 256ull;
    char* w = (char*)d_ws;

    bf16* x_bf  = (bf16*)(w + 0 * U * 2);
    bf16* s_bf  = (bf16*)(w + 1 * U * 2);
    bf16* msgln = (bf16*)(w + 2 * U * 2);
    bf16* t_bf  = (bf16*)(w + 3 * U * 2);   // slots 3-4 ([32768,512])

    char* wx = w + 7 * U * 2;
    bf16* WqT = (bf16*)wx; wx += 65536 * 2;
    bf16* WkT = (bf16*)wx; wx += 65536 * 2;   // contiguous with WvT
    bf16* WvT = (bf16*)wx; wx += 65536 * 2;
    bf16* WmT = (bf16*)wx; wx += 65536 * 2;
    bf16* W1T = (bf16*)wx; wx += 262144 * 2;
    bf16* W2T = (bf16*)wx; wx += 131072 * 2;
    bf16* partKV = (bf16*)wx; wx += 2097152 * 2;   // 256 cid x 8192
    float* partKs = (float*)wx; wx += 65536 * 4;   // 256 cid x 256
    bf16* KVb    = (bf16*)wx; wx += 49152 * 2;     // [n][h][32][48]

    const dim3 blk(256);

    // 1) prep
    k_prep<<<8352, blk, 0, stream>>>(x, source, x_bf, s_bf,
                                     Wq, Wk, Wv, Wm, W1, W2,
                                     WqT, WkT, WvT, WmT, W1T, W2T);

    // 2) fused K/V projection + partial KV/Ksum
    k_kvproj<<<dim3(256, 2), dim3(512), 0, stream>>>(s_bf, WkT, partKV, partKs,
                                                     1.f / 8192.f);

    // 3) MERGED reduce -> KVaug (one launch, 1024 thr, fp32 accum)
    k_kvredM<<<32, dim3(1024), 0, stream>>>(partKV, partKs, KVb);

    // 4) MEGA: Q-proj + attn + merge + LN1 -> msgln
    k_qaml<<<512, dim3(512), 0, stream>>>(x_bf, WqT, WmT, KVb, g1, b1, msgln);

    // 5) MLP: 8-phase W1; 8-phase W2+LN2+residual
    k_gemmW1_8p<<<dim3(128, 2), dim3(512), 0, stream>>>(x_bf, msgln, W1T, t_bf);
    k_ln2_8p<<<128, dim3(512), 0, stream>>>(t_bf, W2T, g2, b2, x, out);
}